// Round 1
// baseline (497.377 us; speedup 1.0000x reference)
//
#include <hip/hip_runtime.h>
#include <hip/hip_bf16.h>

#define B_ 4
#define S_ 4096
#define D_ 1024
#define E_ 8
#define F_ 2048
#define TK_ 512

typedef unsigned short u16;
typedef unsigned int u32;
typedef u16 u16x8 __attribute__((ext_vector_type(8)));
typedef short s16x8 __attribute__((ext_vector_type(8)));
typedef float f32x4 __attribute__((ext_vector_type(4)));

__device__ __forceinline__ u16 f2bf(float f) {
  u32 u = __builtin_bit_cast(u32, f);
  u32 r = (u + 0x7fffu + ((u >> 16) & 1u)) >> 16;
  return (u16)r;
}
__device__ __forceinline__ float b2f(u16 h) {
  return __builtin_bit_cast(float, ((u32)h) << 16);
}
__device__ __forceinline__ void gload16(const void* g, void* l) {
  __builtin_amdgcn_global_load_lds((const __attribute__((address_space(1))) void*)g,
                                   (__attribute__((address_space(3))) void*)l, 16, 0, 0);
}
__device__ __forceinline__ f32x4 mfma_bf16(s16x8 a, s16x8 b, f32x4 c) {
  return __builtin_amdgcn_mfma_f32_16x16x32_bf16(a, b, c, 0, 0, 0);
}

// ---------------- router: logits = x @ Wr ----------------
__global__ __launch_bounds__(256) void router_kernel(const float* __restrict__ x,
                                                     const float* __restrict__ Wr,
                                                     float* __restrict__ logits) {
  __shared__ float wr[D_ * E_];
  for (int i = threadIdx.x; i < D_ * E_; i += 256) wr[i] = Wr[i];
  __syncthreads();
  int lane = threadIdx.x & 63;
  int wid = threadIdx.x >> 6;
  int token = blockIdx.x * 4 + wid;  // 16384 tokens total
  const float* xr = x + (size_t)token * D_;
  float acc[E_];
#pragma unroll
  for (int e = 0; e < E_; ++e) acc[e] = 0.f;
#pragma unroll
  for (int q = 0; q < 4; ++q) {
    int d0 = q * 256 + lane * 4;
    float4 v = *(const float4*)(xr + d0);
    float xv[4] = {v.x, v.y, v.z, v.w};
    const float* w0 = &wr[d0 * E_];
#pragma unroll
    for (int j = 0; j < 4; ++j) {
#pragma unroll
      for (int e = 0; e < E_; ++e) acc[e] += xv[j] * w0[j * E_ + e];
    }
  }
#pragma unroll
  for (int e = 0; e < E_; ++e) {
#pragma unroll
    for (int off = 32; off; off >>= 1) acc[e] += __shfl_down(acc[e], off);
  }
  if (lane == 0) {
    float4 o0 = make_float4(acc[0], acc[1], acc[2], acc[3]);
    float4 o1 = make_float4(acc[4], acc[5], acc[6], acc[7]);
    *(float4*)(logits + (size_t)token * E_) = o0;
    *(float4*)(logits + (size_t)token * E_ + 4) = o1;
  }
}

// ---------------- top-k per (b,e): bitonic sort of 4096 probs ----------------
__global__ __launch_bounds__(1024) void topk_kernel(const float* __restrict__ logits,
                                                    int* __restrict__ idx,
                                                    float* __restrict__ wts) {
  int be = blockIdx.x, b = be >> 3, e = be & 7;
  __shared__ float pv[S_];
  __shared__ u16 pi[S_];
  const float* lg = logits + (size_t)b * S_ * E_;
  for (int s = threadIdx.x; s < S_; s += 1024) {
    float4 l0 = *(const float4*)(lg + (size_t)s * E_);
    float4 l1 = *(const float4*)(lg + (size_t)s * E_ + 4);
    float la[8] = {l0.x, l0.y, l0.z, l0.w, l1.x, l1.y, l1.z, l1.w};
    float mx = la[0];
#pragma unroll
    for (int t = 1; t < 8; ++t) mx = fmaxf(mx, la[t]);
    float sum = 0.f;
#pragma unroll
    for (int t = 0; t < 8; ++t) sum += expf(la[t] - mx);
    float p = expf(la[e] - mx) / sum;
    pv[s] = p;
    pi[s] = (u16)s;
  }
  __syncthreads();
  // bitonic sort: descending by (p, then index ascending)
  for (int k = 2; k <= S_; k <<= 1) {
    for (int j = k >> 1; j > 0; j >>= 1) {
      for (int i = threadIdx.x; i < S_; i += 1024) {
        int l = i ^ j;
        if (l > i) {
          float va = pv[i], vb = pv[l];
          u16 ia = pi[i], ib = pi[l];
          bool ok = (va > vb) || (va == vb && ia < ib);  // desired order a-then-b
          bool up = ((i & k) == 0);
          if (up ? !ok : ok) {
            pv[i] = vb; pv[l] = va;
            pi[i] = ib; pi[l] = ia;
          }
        }
      }
      __syncthreads();
    }
  }
  for (int t = threadIdx.x; t < TK_; t += 1024) {
    idx[be * TK_ + t] = (int)pi[t];
    wts[be * TK_ + t] = pv[t];
  }
}

// ---------------- transpose + f32->bf16: dst[c][r] = src[r][c] per expert ----------------
__global__ __launch_bounds__(256) void transpose_cvt_kernel(const float* __restrict__ src,
                                                            u16* __restrict__ dst,
                                                            int R, int C) {
  __shared__ float tile[32][33];
  int z = blockIdx.z;
  const float* s = src + (size_t)z * R * C;
  u16* d = dst + (size_t)z * R * C;
  int r0 = blockIdx.x * 32, c0 = blockIdx.y * 32;
  int xx = threadIdx.x & 31, yy = threadIdx.x >> 5;
#pragma unroll
  for (int q = 0; q < 4; ++q)
    tile[yy + q * 8][xx] = s[(size_t)(r0 + yy + q * 8) * C + c0 + xx];
  __syncthreads();
#pragma unroll
  for (int q = 0; q < 4; ++q)
    d[(size_t)(c0 + yy + q * 8) * R + r0 + xx] = f2bf(tile[xx][yy + q * 8]);
}

// ---------------- GEMM1: h = gelu(gather(x) @ W1t^T + b1), bf16 out ----------------
__global__ __launch_bounds__(256) void gemm1_kernel(const float* __restrict__ x,
                                                    const u16* __restrict__ W1t,
                                                    const float* __restrict__ b1,
                                                    const int* __restrict__ idx,
                                                    u16* __restrict__ hbuf) {
  int be = blockIdx.y, bb = be >> 3, e = be & 7;
  int tm = blockIdx.x & 3, tn = blockIdx.x >> 2;  // 4 x 16 tiles
  int t0 = tm * 128, n0 = tn * 128;
  int tid = threadIdx.x, lane = tid & 63, wid = tid >> 6;
  int wm = wid & 1, wn = wid >> 1;
  int cidx = lane & 15, kq = lane >> 4;
  __shared__ __align__(16) u16 As[128][40];  // padded: 2-way-free frag reads
  __shared__ __align__(16) u16 Bs[128 * 32];
  int ar = tid >> 1;
  int akh = (tid & 1) << 4;
  int tok = idx[be * TK_ + t0 + ar];
  const float* arow = x + ((size_t)bb * S_ + tok) * D_;
  const u16* bsrc = W1t + (size_t)e * F_ * D_;
  f32x4 zero = {0.f, 0.f, 0.f, 0.f};
  f32x4 acc[4][4];
#pragma unroll
  for (int i = 0; i < 4; ++i)
#pragma unroll
    for (int j = 0; j < 4; ++j) acc[i][j] = zero;

  for (int k0 = 0; k0 < D_; k0 += 32) {
    // stage B via global_load_lds (linear LDS dest, per-lane global src)
#pragma unroll
    for (int it = 0; it < 2; ++it) {
      int c = (wid * 2 + it) * 64 + lane;
      const u16* g = bsrc + (size_t)(n0 + (c >> 2)) * D_ + k0 + (c & 3) * 8;
      gload16(g, &Bs[(wid * 2 + it) * 512]);
    }
    // stage A: gathered f32 row -> cvt bf16 -> LDS
    const float* ap = arow + k0 + akh;
    float4 v0 = *(const float4*)(ap);
    float4 v1 = *(const float4*)(ap + 4);
    float4 v2 = *(const float4*)(ap + 8);
    float4 v3 = *(const float4*)(ap + 12);
    u16x8 p0, p1;
    p0[0] = f2bf(v0.x); p0[1] = f2bf(v0.y); p0[2] = f2bf(v0.z); p0[3] = f2bf(v0.w);
    p0[4] = f2bf(v1.x); p0[5] = f2bf(v1.y); p0[6] = f2bf(v1.z); p0[7] = f2bf(v1.w);
    p1[0] = f2bf(v2.x); p1[1] = f2bf(v2.y); p1[2] = f2bf(v2.z); p1[3] = f2bf(v2.w);
    p1[4] = f2bf(v3.x); p1[5] = f2bf(v3.y); p1[6] = f2bf(v3.z); p1[7] = f2bf(v3.w);
    *(u16x8*)&As[ar][akh] = p0;
    *(u16x8*)&As[ar][akh + 8] = p1;
    __syncthreads();
    s16x8 aF[4], bF[4];
#pragma unroll
    for (int f = 0; f < 4; ++f)
      aF[f] = *(const s16x8*)&As[wm * 64 + f * 16 + cidx][kq * 8];
#pragma unroll
    for (int f = 0; f < 4; ++f)
      bF[f] = *(const s16x8*)&Bs[(wn * 64 + f * 16 + cidx) * 32 + kq * 8];
#pragma unroll
    for (int i = 0; i < 4; ++i)
#pragma unroll
      for (int j = 0; j < 4; ++j) acc[i][j] = mfma_bf16(aF[i], bF[j], acc[i][j]);
    __syncthreads();
  }
  // epilogue: +bias, exact gelu, store bf16
  float bias[4];
#pragma unroll
  for (int j = 0; j < 4; ++j) bias[j] = b1[e * F_ + n0 + wn * 64 + j * 16 + cidx];
#pragma unroll
  for (int i = 0; i < 4; ++i) {
#pragma unroll
    for (int r = 0; r < 4; ++r) {
      int trow = t0 + wm * 64 + i * 16 + kq * 4 + r;
      size_t hb = ((size_t)be * TK_ + trow) * F_ + n0 + wn * 64 + cidx;
#pragma unroll
      for (int j = 0; j < 4; ++j) {
        float v = acc[i][j][r] + bias[j];
        float gl = 0.5f * v * (1.0f + erff(v * 0.70710678118654752f));
        hbuf[hb + j * 16] = f2bf(gl);
      }
    }
  }
}

// ---------------- LayerNorm in place on h (wave per row) ----------------
__global__ __launch_bounds__(256) void norm_kernel(u16* __restrict__ hbuf,
                                                   const float* __restrict__ gamma,
                                                   const float* __restrict__ beta) {
  int row = blockIdx.x * 4 + (threadIdx.x >> 6);  // 16384 rows
  int lane = threadIdx.x & 63;
  int e = (row >> 9) & 7;
  u16* hr = hbuf + (size_t)row * F_;
  u16x8 raw[4];
  float sum = 0.f, ss = 0.f;
#pragma unroll
  for (int q = 0; q < 4; ++q) {
    raw[q] = *(const u16x8*)(hr + (q * 64 + lane) * 8);
#pragma unroll
    for (int j = 0; j < 8; ++j) {
      float v = b2f(raw[q][j]);
      sum += v;
      ss += v * v;
    }
  }
#pragma unroll
  for (int off = 32; off; off >>= 1) {
    sum += __shfl_down(sum, off);
    ss += __shfl_down(ss, off);
  }
  sum = __shfl(sum, 0);
  ss = __shfl(ss, 0);
  float mean = sum * (1.f / F_);
  float var = ss * (1.f / F_) - mean * mean;
  float rstd = rsqrtf(var + 1e-5f);
#pragma unroll
  for (int q = 0; q < 4; ++q) {
    int fb = (q * 64 + lane) * 8;
    const float* gr = gamma + (size_t)e * F_ + fb;
    const float* br = beta + (size_t)e * F_ + fb;
    float4 g0 = *(const float4*)gr, g1 = *(const float4*)(gr + 4);
    float4 t0 = *(const float4*)br, t1 = *(const float4*)(br + 4);
    float ga[8] = {g0.x, g0.y, g0.z, g0.w, g1.x, g1.y, g1.z, g1.w};
    float bt[8] = {t0.x, t0.y, t0.z, t0.w, t1.x, t1.y, t1.z, t1.w};
    u16x8 o;
#pragma unroll
    for (int j = 0; j < 8; ++j) {
      float v = (b2f(raw[q][j]) - mean) * rstd * ga[j] + bt[j];
      o[j] = f2bf(v);
    }
    *(u16x8*)(hr + (q * 64 + lane) * 8) = o;
  }
}

// ---------------- GEMM2: out = hn @ W2t^T + b2 -> weighted scatter-add ----------------
__global__ __launch_bounds__(256) void gemm2_kernel(const u16* __restrict__ hbuf,
                                                    const u16* __restrict__ W2t,
                                                    const float* __restrict__ b2,
                                                    const int* __restrict__ idx,
                                                    const float* __restrict__ wts,
                                                    float* __restrict__ results) {
  int be = blockIdx.y, bb = be >> 3, e = be & 7;
  int tm = blockIdx.x & 3, tn = blockIdx.x >> 2;  // 4 x 8 tiles
  int t0 = tm * 128, n0 = tn * 128;
  int tid = threadIdx.x, lane = tid & 63, wid = tid >> 6;
  int wm = wid & 1, wn = wid >> 1;
  int cidx = lane & 15, kq = lane >> 4;
  __shared__ __align__(16) u16 As[128 * 32];
  __shared__ __align__(16) u16 Bs[128 * 32];
  const u16* asrc = hbuf + (size_t)be * TK_ * F_;
  const u16* bsrc = W2t + (size_t)e * D_ * F_;
  f32x4 zero = {0.f, 0.f, 0.f, 0.f};
  f32x4 acc[4][4];
#pragma unroll
  for (int i = 0; i < 4; ++i)
#pragma unroll
    for (int j = 0; j < 4; ++j) acc[i][j] = zero;

  for (int k0 = 0; k0 < F_; k0 += 32) {
#pragma unroll
    for (int it = 0; it < 2; ++it) {
      int c = (wid * 2 + it) * 64 + lane;
      const u16* ga = asrc + (size_t)(t0 + (c >> 2)) * F_ + k0 + (c & 3) * 8;
      gload16(ga, &As[(wid * 2 + it) * 512]);
      const u16* gb = bsrc + (size_t)(n0 + (c >> 2)) * F_ + k0 + (c & 3) * 8;
      gload16(gb, &Bs[(wid * 2 + it) * 512]);
    }
    __syncthreads();
    s16x8 aF[4], bF[4];
#pragma unroll
    for (int f = 0; f < 4; ++f)
      aF[f] = *(const s16x8*)&As[(wm * 64 + f * 16 + cidx) * 32 + kq * 8];
#pragma unroll
    for (int f = 0; f < 4; ++f)
      bF[f] = *(const s16x8*)&Bs[(wn * 64 + f * 16 + cidx) * 32 + kq * 8];
#pragma unroll
    for (int i = 0; i < 4; ++i)
#pragma unroll
      for (int j = 0; j < 4; ++j) acc[i][j] = mfma_bf16(aF[i], bF[j], acc[i][j]);
    __syncthreads();
  }
  // epilogue: weighted scatter-add with atomics
  int tkA[4][4];
  float wvA[4][4];
#pragma unroll
  for (int i = 0; i < 4; ++i)
#pragma unroll
    for (int r = 0; r < 4; ++r) {
      int trow = t0 + wm * 64 + i * 16 + kq * 4 + r;
      tkA[i][r] = idx[be * TK_ + trow];
      wvA[i][r] = wts[be * TK_ + trow];
    }
  float bias[4];
#pragma unroll
  for (int j = 0; j < 4; ++j) bias[j] = b2[e * D_ + n0 + wn * 64 + j * 16 + cidx];
#pragma unroll
  for (int i = 0; i < 4; ++i)
#pragma unroll
    for (int r = 0; r < 4; ++r) {
      float* rrow = results + ((size_t)bb * S_ + tkA[i][r]) * D_ + n0 + wn * 64 + cidx;
#pragma unroll
      for (int j = 0; j < 4; ++j) {
        float val = wvA[i][r] * (acc[i][j][r] + bias[j]);
        unsafeAtomicAdd(rrow + j * 16, val);
      }
    }
}

extern "C" void kernel_launch(void* const* d_in, const int* in_sizes, int n_in,
                              void* d_out, int out_size, void* d_ws, size_t ws_size,
                              hipStream_t stream) {
  const float* x = (const float*)d_in[0];
  const float* Wr = (const float*)d_in[1];
  const float* W1 = (const float*)d_in[2];
  const float* b1 = (const float*)d_in[3];
  const float* gamma = (const float*)d_in[4];
  const float* beta = (const float*)d_in[5];
  const float* W2 = (const float*)d_in[6];
  const float* b2 = (const float*)d_in[7];

  float* results = (float*)d_out;
  float* logits = results + (size_t)B_ * S_ * D_;

  // workspace layout
  char* ws = (char*)d_ws;
  const size_t OFF_IDX = 0;
  const size_t OFF_WTS = OFF_IDX + (size_t)B_ * E_ * TK_ * 4;            // 64 KiB
  const size_t OFF_W1T = OFF_WTS + (size_t)B_ * E_ * TK_ * 4;            // 128 KiB
  const size_t OFF_W2T = OFF_W1T + (size_t)E_ * D_ * F_ * 2;             // +32 MiB
  const size_t OFF_H = OFF_W2T + (size_t)E_ * D_ * F_ * 2;               // +32 MiB
  const size_t NEED = OFF_H + (size_t)B_ * E_ * TK_ * F_ * 2;            // +64 MiB
  if (ws_size < NEED) return;  // insufficient scratch -> bail (will fail validation loudly)

  int* idx = (int*)(ws + OFF_IDX);
  float* wts = (float*)(ws + OFF_WTS);
  u16* W1t = (u16*)(ws + OFF_W1T);
  u16* W2t = (u16*)(ws + OFF_W2T);
  u16* hbuf = (u16*)(ws + OFF_H);

  hipMemsetAsync(d_out, 0, (size_t)B_ * S_ * D_ * sizeof(float), stream);

  router_kernel<<<dim3(B_ * S_ / 4), 256, 0, stream>>>(x, Wr, logits);
  topk_kernel<<<dim3(B_ * E_), 1024, 0, stream>>>(logits, idx, wts);
  transpose_cvt_kernel<<<dim3(D_ / 32, F_ / 32, E_), 256, 0, stream>>>(W1, W1t, D_, F_);
  transpose_cvt_kernel<<<dim3(F_ / 32, D_ / 32, E_), 256, 0, stream>>>(W2, W2t, F_, D_);
  gemm1_kernel<<<dim3((TK_ / 128) * (F_ / 128), B_ * E_), 256, 0, stream>>>(x, W1t, b1, idx, hbuf);
  norm_kernel<<<dim3(B_ * E_ * TK_ / 4), 256, 0, stream>>>(hbuf, gamma, beta);
  gemm2_kernel<<<dim3((TK_ / 128) * (D_ / 128), B_ * E_), 256, 0, stream>>>(hbuf, W2t, b2, idx, wts, results);
}

// Round 2
// 447.968 us; speedup vs baseline: 1.1103x; 1.1103x over previous
//
#include <hip/hip_runtime.h>
#include <hip/hip_bf16.h>

#define B_ 4
#define S_ 4096
#define D_ 1024
#define E_ 8
#define F_ 2048
#define TK_ 512

#define BM 256
#define BN 256
#define BK 64

typedef unsigned short u16;
typedef unsigned int u32;
typedef u16 u16x8 __attribute__((ext_vector_type(8)));
typedef short s16x8 __attribute__((ext_vector_type(8)));
typedef float f32x4 __attribute__((ext_vector_type(4)));

__device__ __forceinline__ u16 f2bf(float f) {
  u32 u = __builtin_bit_cast(u32, f);
  u32 r = (u + 0x7fffu + ((u >> 16) & 1u)) >> 16;
  return (u16)r;
}
__device__ __forceinline__ float b2f(u16 h) {
  return __builtin_bit_cast(float, ((u32)h) << 16);
}
__device__ __forceinline__ void gload16(const u16* g, const u16* l) {
  __builtin_amdgcn_global_load_lds((const __attribute__((address_space(1))) void*)g,
                                   (__attribute__((address_space(3))) void*)l, 16, 0, 0);
}
__device__ __forceinline__ f32x4 mfma_bf16(s16x8 a, s16x8 b, f32x4 c) {
  return __builtin_amdgcn_mfma_f32_16x16x32_bf16(a, b, c, 0, 0, 0);
}

// ---------------- router: logits = x @ Wr ----------------
__global__ __launch_bounds__(256) void router_kernel(const float* __restrict__ x,
                                                     const float* __restrict__ Wr,
                                                     float* __restrict__ logits) {
  __shared__ float wr[D_ * E_];
  for (int i = threadIdx.x; i < D_ * E_; i += 256) wr[i] = Wr[i];
  __syncthreads();
  int lane = threadIdx.x & 63;
  int wid = threadIdx.x >> 6;
  int token = blockIdx.x * 4 + wid;
  const float* xr = x + (size_t)token * D_;
  float acc[E_];
#pragma unroll
  for (int e = 0; e < E_; ++e) acc[e] = 0.f;
#pragma unroll
  for (int q = 0; q < 4; ++q) {
    int d0 = q * 256 + lane * 4;
    float4 v = *(const float4*)(xr + d0);
    float xv[4] = {v.x, v.y, v.z, v.w};
    const float* w0 = &wr[d0 * E_];
#pragma unroll
    for (int j = 0; j < 4; ++j) {
#pragma unroll
      for (int e = 0; e < E_; ++e) acc[e] += xv[j] * w0[j * E_ + e];
    }
  }
#pragma unroll
  for (int e = 0; e < E_; ++e) {
#pragma unroll
    for (int off = 32; off; off >>= 1) acc[e] += __shfl_down(acc[e], off);
  }
  if (lane == 0) {
    float4 o0 = make_float4(acc[0], acc[1], acc[2], acc[3]);
    float4 o1 = make_float4(acc[4], acc[5], acc[6], acc[7]);
    *(float4*)(logits + (size_t)token * E_) = o0;
    *(float4*)(logits + (size_t)token * E_ + 4) = o1;
  }
}

// ---------------- top-k per (b,e): bitonic sort of 4096 probs ----------------
__global__ __launch_bounds__(1024) void topk_kernel(const float* __restrict__ logits,
                                                    int* __restrict__ idx,
                                                    float* __restrict__ wts) {
  int be = blockIdx.x, b = be >> 3, e = be & 7;
  __shared__ float pv[S_];
  __shared__ u16 pi[S_];
  const float* lg = logits + (size_t)b * S_ * E_;
  for (int s = threadIdx.x; s < S_; s += 1024) {
    float4 l0 = *(const float4*)(lg + (size_t)s * E_);
    float4 l1 = *(const float4*)(lg + (size_t)s * E_ + 4);
    float la[8] = {l0.x, l0.y, l0.z, l0.w, l1.x, l1.y, l1.z, l1.w};
    float mx = la[0];
#pragma unroll
    for (int t = 1; t < 8; ++t) mx = fmaxf(mx, la[t]);
    float sum = 0.f;
#pragma unroll
    for (int t = 0; t < 8; ++t) sum += expf(la[t] - mx);
    float p = expf(la[e] - mx) / sum;
    pv[s] = p;
    pi[s] = (u16)s;
  }
  __syncthreads();
  for (int k = 2; k <= S_; k <<= 1) {
    for (int j = k >> 1; j > 0; j >>= 1) {
      for (int i = threadIdx.x; i < S_; i += 1024) {
        int l = i ^ j;
        if (l > i) {
          float va = pv[i], vb = pv[l];
          u16 ia = pi[i], ib = pi[l];
          bool ok = (va > vb) || (va == vb && ia < ib);
          bool up = ((i & k) == 0);
          if (up ? !ok : ok) {
            pv[i] = vb; pv[l] = va;
            pi[i] = ib; pi[l] = ia;
          }
        }
      }
      __syncthreads();
    }
  }
  for (int t = threadIdx.x; t < TK_; t += 1024) {
    idx[be * TK_ + t] = (int)pi[t];
    wts[be * TK_ + t] = pv[t];
  }
}

// ---------------- x f32 -> bf16 ----------------
__global__ __launch_bounds__(256) void cvt_bf16_kernel(const float* __restrict__ src,
                                                       u16* __restrict__ dst) {
  size_t i = ((size_t)blockIdx.x * 256 + threadIdx.x) * 8;
  float4 v0 = *(const float4*)(src + i);
  float4 v1 = *(const float4*)(src + i + 4);
  u16x8 o;
  o[0] = f2bf(v0.x); o[1] = f2bf(v0.y); o[2] = f2bf(v0.z); o[3] = f2bf(v0.w);
  o[4] = f2bf(v1.x); o[5] = f2bf(v1.y); o[6] = f2bf(v1.z); o[7] = f2bf(v1.w);
  *(u16x8*)(dst + i) = o;
}

// ---------------- transpose + f32->bf16: dst[c][r] = src[r][c] per expert ----------------
__global__ __launch_bounds__(256) void transpose_cvt_kernel(const float* __restrict__ src,
                                                            u16* __restrict__ dst,
                                                            int R, int C) {
  __shared__ float tile[32][33];
  int z = blockIdx.z;
  const float* s = src + (size_t)z * R * C;
  u16* d = dst + (size_t)z * R * C;
  int r0 = blockIdx.x * 32, c0 = blockIdx.y * 32;
  int xx = threadIdx.x & 31, yy = threadIdx.x >> 5;
#pragma unroll
  for (int q = 0; q < 4; ++q)
    tile[yy + q * 8][xx] = s[(size_t)(r0 + yy + q * 8) * C + c0 + xx];
  __syncthreads();
#pragma unroll
  for (int q = 0; q < 4; ++q)
    d[(size_t)(c0 + yy + q * 8) * R + r0 + xx] = f2bf(tile[xx][yy + q * 8]);
}

// ---------------- shared 2-phase 256x256x64 MFMA K-loop ----------------
// A/B staged via global_load_lds (linear LDS dest); XOR swizzle kc = slot^(row&7)
// applied on the global SOURCE and the ds_read (both-sides, rule 21).
__device__ __forceinline__ void gemm_kloop(const u16* agp[4], const u16* bgp[4],
                                           const int loff[4], u16 (*As)[BM * BK],
                                           u16 (*Bs)[BM * BK], f32x4 acc[8][4],
                                           int NT, int wm, int wn, int cidx, int kq) {
#pragma unroll
  for (int q = 0; q < 4; ++q) {
    gload16(agp[q], &As[0][loff[q]]);
    gload16(bgp[q], &Bs[0][loff[q]]);
  }
  __syncthreads();
  int cur = 0;
  int sw = cidx & 7;
  for (int t = 0; t < NT; ++t) {
    if (t + 1 < NT) {
      int k0 = (t + 1) * BK;
#pragma unroll
      for (int q = 0; q < 4; ++q) {
        gload16(agp[q] + k0, &As[cur ^ 1][loff[q]]);
        gload16(bgp[q] + k0, &Bs[cur ^ 1][loff[q]]);
      }
    }
    const u16* Ab = As[cur];
    const u16* Bb = Bs[cur];
#pragma unroll
    for (int kk = 0; kk < 2; ++kk) {
      int s = (kk * 4 + kq) ^ sw;
      s16x8 aF[8], bF[4];
#pragma unroll
      for (int f = 0; f < 8; ++f)
        aF[f] = *(const s16x8*)&Ab[(wm * 128 + f * 16 + cidx) * 64 + s * 8];
#pragma unroll
      for (int g = 0; g < 4; ++g)
        bF[g] = *(const s16x8*)&Bb[(wn * 64 + g * 16 + cidx) * 64 + s * 8];
#pragma unroll
      for (int f = 0; f < 8; ++f)
#pragma unroll
        for (int g = 0; g < 4; ++g) acc[f][g] = mfma_bf16(aF[f], bF[g], acc[f][g]);
    }
    __syncthreads();
    cur ^= 1;
  }
}

// ---------------- GEMM1: h = gelu(gather(xb) @ W1t^T + b1) ----------------
__global__ __launch_bounds__(512, 2) void gemm1_kernel(const u16* __restrict__ xb,
                                                       const u16* __restrict__ W1t,
                                                       const float* __restrict__ b1,
                                                       const int* __restrict__ idx,
                                                       u16* __restrict__ hbuf) {
  int be = blockIdx.y, bb = be >> 3, e = be & 7;
  int tm = blockIdx.x & 1, tn = blockIdx.x >> 1;  // 2 x 8
  int t0 = tm * BM, n0 = tn * BN;
  int tid = threadIdx.x, lane = tid & 63, wid = tid >> 6;
  int wm = wid >> 2, wn = wid & 3;
  int cidx = lane & 15, kq = lane >> 4;
  __shared__ u16 As[2][BM * BK];
  __shared__ u16 Bs[2][BM * BK];
  const u16* agp[4];
  const u16* bgp[4];
  int loff[4];
  const u16* bsrc = W1t + (size_t)e * F_ * D_;
#pragma unroll
  for (int q = 0; q < 4; ++q) {
    int slot = q * 512 + wid * 64 + lane;
    int row = slot >> 3, sl = slot & 7, kc = sl ^ (row & 7);
    int tok = idx[be * TK_ + t0 + row];
    agp[q] = xb + ((size_t)bb * S_ + tok) * D_ + kc * 8;
    bgp[q] = bsrc + (size_t)(n0 + row) * D_ + kc * 8;
    loff[q] = (q * 512 + wid * 64) * 8;
  }
  f32x4 acc[8][4];
#pragma unroll
  for (int f = 0; f < 8; ++f)
#pragma unroll
    for (int g = 0; g < 4; ++g) acc[f][g] = (f32x4){0.f, 0.f, 0.f, 0.f};

  gemm_kloop(agp, bgp, loff, As, Bs, acc, D_ / BK, wm, wn, cidx, kq);

  float bias[4];
#pragma unroll
  for (int g = 0; g < 4; ++g) bias[g] = b1[e * F_ + n0 + wn * 64 + g * 16 + cidx];
  size_t hbase = (size_t)be * TK_ * F_;
#pragma unroll
  for (int f = 0; f < 8; ++f) {
#pragma unroll
    for (int r = 0; r < 4; ++r) {
      int trow = t0 + wm * 128 + f * 16 + kq * 4 + r;
      size_t hb = hbase + (size_t)trow * F_ + n0 + wn * 64 + cidx;
#pragma unroll
      for (int g = 0; g < 4; ++g) {
        float v = acc[f][g][r] + bias[g];
        float gl = 0.5f * v * (1.0f + erff(v * 0.70710678118654752f));
        hbuf[hb + g * 16] = f2bf(gl);
      }
    }
  }
}

// ---------------- LayerNorm in place on h (wave per row) ----------------
__global__ __launch_bounds__(256) void norm_kernel(u16* __restrict__ hbuf,
                                                   const float* __restrict__ gamma,
                                                   const float* __restrict__ beta) {
  int row = blockIdx.x * 4 + (threadIdx.x >> 6);
  int lane = threadIdx.x & 63;
  int e = (row >> 9) & 7;
  u16* hr = hbuf + (size_t)row * F_;
  u16x8 raw[4];
  float sum = 0.f, ss = 0.f;
#pragma unroll
  for (int q = 0; q < 4; ++q) {
    raw[q] = *(const u16x8*)(hr + (q * 64 + lane) * 8);
#pragma unroll
    for (int j = 0; j < 8; ++j) {
      float v = b2f(raw[q][j]);
      sum += v;
      ss += v * v;
    }
  }
#pragma unroll
  for (int off = 32; off; off >>= 1) {
    sum += __shfl_down(sum, off);
    ss += __shfl_down(ss, off);
  }
  sum = __shfl(sum, 0);
  ss = __shfl(ss, 0);
  float mean = sum * (1.f / F_);
  float var = ss * (1.f / F_) - mean * mean;
  float rstd = rsqrtf(var + 1e-5f);
#pragma unroll
  for (int q = 0; q < 4; ++q) {
    int fb = (q * 64 + lane) * 8;
    const float* gr = gamma + (size_t)e * F_ + fb;
    const float* br = beta + (size_t)e * F_ + fb;
    float4 g0 = *(const float4*)gr, g1 = *(const float4*)(gr + 4);
    float4 t0 = *(const float4*)br, t1 = *(const float4*)(br + 4);
    float ga[8] = {g0.x, g0.y, g0.z, g0.w, g1.x, g1.y, g1.z, g1.w};
    float bt[8] = {t0.x, t0.y, t0.z, t0.w, t1.x, t1.y, t1.z, t1.w};
    u16x8 o;
#pragma unroll
    for (int j = 0; j < 8; ++j) {
      float v = (b2f(raw[q][j]) - mean) * rstd * ga[j] + bt[j];
      o[j] = f2bf(v);
    }
    *(u16x8*)(hr + (q * 64 + lane) * 8) = o;
  }
}

// ---------------- GEMM2: out = hn @ W2t^T + b2 -> weighted scatter-add ----------------
__global__ __launch_bounds__(512, 2) void gemm2_kernel(const u16* __restrict__ hbuf,
                                                       const u16* __restrict__ W2t,
                                                       const float* __restrict__ b2,
                                                       const int* __restrict__ idx,
                                                       const float* __restrict__ wts,
                                                       float* __restrict__ results) {
  int be = blockIdx.y, bb = be >> 3, e = be & 7;
  int tm = blockIdx.x & 1, tn = blockIdx.x >> 1;  // 2 x 4
  int t0 = tm * BM, n0 = tn * BN;
  int tid = threadIdx.x, lane = tid & 63, wid = tid >> 6;
  int wm = wid >> 2, wn = wid & 3;
  int cidx = lane & 15, kq = lane >> 4;
  __shared__ u16 As[2][BM * BK];
  __shared__ u16 Bs[2][BM * BK];
  const u16* agp[4];
  const u16* bgp[4];
  int loff[4];
  const u16* asrc = hbuf + (size_t)be * TK_ * F_;
  const u16* bsrc = W2t + (size_t)e * D_ * F_;
#pragma unroll
  for (int q = 0; q < 4; ++q) {
    int slot = q * 512 + wid * 64 + lane;
    int row = slot >> 3, sl = slot & 7, kc = sl ^ (row & 7);
    agp[q] = asrc + (size_t)(t0 + row) * F_ + kc * 8;
    bgp[q] = bsrc + (size_t)(n0 + row) * F_ + kc * 8;
    loff[q] = (q * 512 + wid * 64) * 8;
  }
  f32x4 acc[8][4];
#pragma unroll
  for (int f = 0; f < 8; ++f)
#pragma unroll
    for (int g = 0; g < 4; ++g) acc[f][g] = (f32x4){0.f, 0.f, 0.f, 0.f};

  gemm_kloop(agp, bgp, loff, As, Bs, acc, F_ / BK, wm, wn, cidx, kq);

  float bias[4];
#pragma unroll
  for (int g = 0; g < 4; ++g) bias[g] = b2[e * D_ + n0 + wn * 64 + g * 16 + cidx];
#pragma unroll
  for (int f = 0; f < 8; ++f) {
#pragma unroll
    for (int r = 0; r < 4; ++r) {
      int trow = t0 + wm * 128 + f * 16 + kq * 4 + r;
      int tok = idx[be * TK_ + trow];
      float wv = wts[be * TK_ + trow];
      float* rrow = results + ((size_t)bb * S_ + tok) * D_ + n0 + wn * 64 + cidx;
#pragma unroll
      for (int g = 0; g < 4; ++g) {
        float val = wv * (acc[f][g][r] + bias[g]);
        unsafeAtomicAdd(rrow + g * 16, val);
      }
    }
  }
}

extern "C" void kernel_launch(void* const* d_in, const int* in_sizes, int n_in,
                              void* d_out, int out_size, void* d_ws, size_t ws_size,
                              hipStream_t stream) {
  const float* x = (const float*)d_in[0];
  const float* Wr = (const float*)d_in[1];
  const float* W1 = (const float*)d_in[2];
  const float* b1 = (const float*)d_in[3];
  const float* gamma = (const float*)d_in[4];
  const float* beta = (const float*)d_in[5];
  const float* W2 = (const float*)d_in[6];
  const float* b2 = (const float*)d_in[7];

  float* results = (float*)d_out;
  float* logits = results + (size_t)B_ * S_ * D_;

  // workspace layout (R0 is reused: xb for gemm1, then W2t for gemm2)
  char* ws = (char*)d_ws;
  const size_t OFF_IDX = 0;
  const size_t OFF_WTS = OFF_IDX + (size_t)B_ * E_ * TK_ * 4;
  const size_t OFF_R0 = OFF_WTS + (size_t)B_ * E_ * TK_ * 4;        // 32 MiB: xb, then W2t
  const size_t OFF_R1 = OFF_R0 + (size_t)E_ * D_ * F_ * 2;          // 32 MiB: W1t
  const size_t OFF_H = OFF_R1 + (size_t)E_ * D_ * F_ * 2;           // 64 MiB: h
  const size_t NEED = OFF_H + (size_t)B_ * E_ * TK_ * F_ * 2;
  if (ws_size < NEED) return;

  int* idx = (int*)(ws + OFF_IDX);
  float* wts = (float*)(ws + OFF_WTS);
  u16* xb = (u16*)(ws + OFF_R0);
  u16* W2t = (u16*)(ws + OFF_R0);
  u16* W1t = (u16*)(ws + OFF_R1);
  u16* hbuf = (u16*)(ws + OFF_H);

  hipMemsetAsync(d_out, 0, (size_t)B_ * S_ * D_ * sizeof(float), stream);

  router_kernel<<<dim3(B_ * S_ / 4), 256, 0, stream>>>(x, Wr, logits);
  topk_kernel<<<dim3(B_ * E_), 1024, 0, stream>>>(logits, idx, wts);
  cvt_bf16_kernel<<<dim3((B_ * S_ * D_) / 2048), 256, 0, stream>>>(x, xb);
  transpose_cvt_kernel<<<dim3(D_ / 32, F_ / 32, E_), 256, 0, stream>>>(W1, W1t, D_, F_);
  gemm1_kernel<<<dim3(2 * (F_ / BN), B_ * E_), 512, 0, stream>>>(xb, W1t, b1, idx, hbuf);
  // W2t overwrites xb region only after gemm1 completed (in-order stream)
  transpose_cvt_kernel<<<dim3(F_ / 32, D_ / 32, E_), 256, 0, stream>>>(W2, W2t, F_, D_);
  norm_kernel<<<dim3(B_ * E_ * TK_ / 4), 256, 0, stream>>>(hbuf, gamma, beta);
  gemm2_kernel<<<dim3(2 * (D_ / BN), B_ * E_), 512, 0, stream>>>(hbuf, W2t, b2, idx, wts, results);
}

// Round 3
// 447.058 us; speedup vs baseline: 1.1126x; 1.0020x over previous
//
#include <hip/hip_runtime.h>
#include <hip/hip_bf16.h>

#define B_ 4
#define S_ 4096
#define D_ 1024
#define E_ 8
#define F_ 2048
#define TK_ 512

typedef unsigned short u16;
typedef unsigned int u32;
typedef u16 u16x8 __attribute__((ext_vector_type(8)));
typedef short s16x8 __attribute__((ext_vector_type(8)));
typedef float f32x4 __attribute__((ext_vector_type(4)));

__device__ __forceinline__ u16 f2bf(float f) {
  u32 u = __builtin_bit_cast(u32, f);
  u32 r = (u + 0x7fffu + ((u >> 16) & 1u)) >> 16;
  return (u16)r;
}
__device__ __forceinline__ float b2f(u16 h) {
  return __builtin_bit_cast(float, ((u32)h) << 16);
}
__device__ __forceinline__ void gload16(const u16* g, const u16* l) {
  __builtin_amdgcn_global_load_lds((const __attribute__((address_space(1))) void*)g,
                                   (__attribute__((address_space(3))) void*)l, 16, 0, 0);
}
__device__ __forceinline__ f32x4 mfma_bf16(s16x8 a, s16x8 b, f32x4 c) {
  return __builtin_amdgcn_mfma_f32_16x16x32_bf16(a, b, c, 0, 0, 0);
}

// ---------------- router: logits = x @ Wr ----------------
__global__ __launch_bounds__(256) void router_kernel(const float* __restrict__ x,
                                                     const float* __restrict__ Wr,
                                                     float* __restrict__ logits) {
  __shared__ float wr[D_ * E_];
  for (int i = threadIdx.x; i < D_ * E_; i += 256) wr[i] = Wr[i];
  __syncthreads();
  int lane = threadIdx.x & 63;
  int wid = threadIdx.x >> 6;
  int token = blockIdx.x * 4 + wid;
  const float* xr = x + (size_t)token * D_;
  float acc[E_];
#pragma unroll
  for (int e = 0; e < E_; ++e) acc[e] = 0.f;
#pragma unroll
  for (int q = 0; q < 4; ++q) {
    int d0 = q * 256 + lane * 4;
    float4 v = *(const float4*)(xr + d0);
    float xv[4] = {v.x, v.y, v.z, v.w};
    const float* w0 = &wr[d0 * E_];
#pragma unroll
    for (int j = 0; j < 4; ++j) {
#pragma unroll
      for (int e = 0; e < E_; ++e) acc[e] += xv[j] * w0[j * E_ + e];
    }
  }
#pragma unroll
  for (int e = 0; e < E_; ++e) {
#pragma unroll
    for (int off = 32; off; off >>= 1) acc[e] += __shfl_down(acc[e], off);
  }
  if (lane == 0) {
    float4 o0 = make_float4(acc[0], acc[1], acc[2], acc[3]);
    float4 o1 = make_float4(acc[4], acc[5], acc[6], acc[7]);
    *(float4*)(logits + (size_t)token * E_) = o0;
    *(float4*)(logits + (size_t)token * E_ + 4) = o1;
  }
}

// ---------------- top-k per (b,e): bitonic sort of 4096 probs ----------------
__global__ __launch_bounds__(1024) void topk_kernel(const float* __restrict__ logits,
                                                    int* __restrict__ idx,
                                                    float* __restrict__ wts) {
  int be = blockIdx.x, b = be >> 3, e = be & 7;
  __shared__ float pv[S_];
  __shared__ u16 pi[S_];
  const float* lg = logits + (size_t)b * S_ * E_;
  for (int s = threadIdx.x; s < S_; s += 1024) {
    float4 l0 = *(const float4*)(lg + (size_t)s * E_);
    float4 l1 = *(const float4*)(lg + (size_t)s * E_ + 4);
    float la[8] = {l0.x, l0.y, l0.z, l0.w, l1.x, l1.y, l1.z, l1.w};
    float mx = la[0];
#pragma unroll
    for (int t = 1; t < 8; ++t) mx = fmaxf(mx, la[t]);
    float sum = 0.f;
#pragma unroll
    for (int t = 0; t < 8; ++t) sum += expf(la[t] - mx);
    float p = expf(la[e] - mx) / sum;
    pv[s] = p;
    pi[s] = (u16)s;
  }
  __syncthreads();
  for (int k = 2; k <= S_; k <<= 1) {
    for (int j = k >> 1; j > 0; j >>= 1) {
      for (int i = threadIdx.x; i < S_; i += 1024) {
        int l = i ^ j;
        if (l > i) {
          float va = pv[i], vb = pv[l];
          u16 ia = pi[i], ib = pi[l];
          bool ok = (va > vb) || (va == vb && ia < ib);
          bool up = ((i & k) == 0);
          if (up ? !ok : ok) {
            pv[i] = vb; pv[l] = va;
            pi[i] = ib; pi[l] = ia;
          }
        }
      }
      __syncthreads();
    }
  }
  for (int t = threadIdx.x; t < TK_; t += 1024) {
    idx[be * TK_ + t] = (int)pi[t];
    wts[be * TK_ + t] = pv[t];
  }
}

// ---------------- x f32 -> bf16 ----------------
__global__ __launch_bounds__(256) void cvt_bf16_kernel(const float* __restrict__ src,
                                                       u16* __restrict__ dst) {
  size_t i = ((size_t)blockIdx.x * 256 + threadIdx.x) * 8;
  float4 v0 = *(const float4*)(src + i);
  float4 v1 = *(const float4*)(src + i + 4);
  u16x8 o;
  o[0] = f2bf(v0.x); o[1] = f2bf(v0.y); o[2] = f2bf(v0.z); o[3] = f2bf(v0.w);
  o[4] = f2bf(v1.x); o[5] = f2bf(v1.y); o[6] = f2bf(v1.z); o[7] = f2bf(v1.w);
  *(u16x8*)(dst + i) = o;
}

// ---------------- transpose + f32->bf16: dst[c][r] = src[r][c] per expert ----------------
__global__ __launch_bounds__(256) void transpose_cvt_kernel(const float* __restrict__ src,
                                                            u16* __restrict__ dst,
                                                            int R, int C) {
  __shared__ float tile[32][33];
  int z = blockIdx.z;
  const float* s = src + (size_t)z * R * C;
  u16* d = dst + (size_t)z * R * C;
  int r0 = blockIdx.x * 32, c0 = blockIdx.y * 32;
  int xx = threadIdx.x & 31, yy = threadIdx.x >> 5;
#pragma unroll
  for (int q = 0; q < 4; ++q)
    tile[yy + q * 8][xx] = s[(size_t)(r0 + yy + q * 8) * C + c0 + xx];
  __syncthreads();
#pragma unroll
  for (int q = 0; q < 4; ++q)
    d[(size_t)(c0 + yy + q * 8) * R + r0 + xx] = f2bf(tile[xx][yy + q * 8]);
}

// =====================================================================
// 8-phase 256x256xK GEMM K-loop (T3+T4+T5). Per K-tile (BK=64): 4 phases
// (m-half x k-half), 16 MFMA each. LDS: [2 buf][2 khalf] 16KB halves per
// operand. Stage 1 half/phase for K-tile t+1; s_waitcnt vmcnt(4) at
// phases 1 and 3 only (counted - loads stay in flight across barriers).
// =====================================================================
#define PH_MH0(bufc, kk, srcp0, srcp1, dstA, koff)                            \
  {                                                                           \
    _Pragma("unroll") for (int fi = 0; fi < 4; ++fi) {                        \
      aF[fi] = *(const s16x8*)&As[bufc][kk][aoff[fi]];                        \
      bF[fi] = *(const s16x8*)&Bs[bufc][kk][boff[fi]];                        \
    }                                                                         \
    gload16(srcp0 + (koff), &dstA[bufc ^ 1][kk][(wid * 64) * 8]);             \
    gload16(srcp1 + (koff), &dstA[bufc ^ 1][kk][(512 + wid * 64) * 8]);       \
    __builtin_amdgcn_s_barrier();                                             \
    __builtin_amdgcn_s_setprio(1);                                            \
    _Pragma("unroll") for (int fi = 0; fi < 4; ++fi)                          \
        _Pragma("unroll") for (int g = 0; g < 4; ++g)                         \
            acc[fi][g] = mfma_bf16(aF[fi], bF[g], acc[fi][g]);                \
    __builtin_amdgcn_s_setprio(0);                                            \
    __builtin_amdgcn_s_barrier();                                             \
  }

#define PH_MH1(bufc, kk, srcp0, srcp1, dstB, koff)                            \
  {                                                                           \
    _Pragma("unroll") for (int fi = 0; fi < 4; ++fi)                          \
        aF[fi] = *(const s16x8*)&As[bufc][kk][aoff[fi] + 2048];               \
    gload16(srcp0 + (koff), &dstB[bufc ^ 1][kk][(wid * 64) * 8]);             \
    gload16(srcp1 + (koff), &dstB[bufc ^ 1][kk][(512 + wid * 64) * 8]);       \
    asm volatile("s_waitcnt vmcnt(4)" ::: "memory");                          \
    __builtin_amdgcn_s_barrier();                                             \
    __builtin_amdgcn_s_setprio(1);                                            \
    _Pragma("unroll") for (int fi = 0; fi < 4; ++fi)                          \
        _Pragma("unroll") for (int g = 0; g < 4; ++g)                         \
            acc[4 + fi][g] = mfma_bf16(aF[fi], bF[g], acc[4 + fi][g]);        \
    __builtin_amdgcn_s_setprio(0);                                            \
    __builtin_amdgcn_s_barrier();                                             \
  }

#define KTILE(bufc, tnext)                                                    \
  {                                                                           \
    s16x8 aF[4], bF[4];                                                       \
    PH_MH0(bufc, 0, pa0, pa1, As, (tnext)*64)                                 \
    PH_MH1(bufc, 0, pb0, pb1, Bs, (tnext)*64)                                 \
    PH_MH0(bufc, 1, pa0, pa1, As, (tnext)*64 + 32)                            \
    PH_MH1(bufc, 1, pb0, pb1, Bs, (tnext)*64 + 32)                            \
  }

__device__ __forceinline__ void kloop8(const u16* pa0, const u16* pa1,
                                       const u16* pb0, const u16* pb1,
                                       u16 (*As)[2][8192], u16 (*Bs)[2][8192],
                                       f32x4 acc[8][4], int NT, int wid,
                                       const int aoff[4], const int boff[4]) {
  // prologue: stage all 4 halves of K-tile 0
  gload16(pa0, &As[0][0][(wid * 64) * 8]);
  gload16(pa1, &As[0][0][(512 + wid * 64) * 8]);
  gload16(pb0, &Bs[0][0][(wid * 64) * 8]);
  gload16(pb1, &Bs[0][0][(512 + wid * 64) * 8]);
  gload16(pa0 + 32, &As[0][1][(wid * 64) * 8]);
  gload16(pa1 + 32, &As[0][1][(512 + wid * 64) * 8]);
  gload16(pb0 + 32, &Bs[0][1][(wid * 64) * 8]);
  gload16(pb1 + 32, &Bs[0][1][(512 + wid * 64) * 8]);
  asm volatile("s_waitcnt vmcnt(4)" ::: "memory");
  __builtin_amdgcn_s_barrier();
  for (int t = 0; t < NT; t += 2) {
    int tn1 = t + 1;
    int tn2 = (t + 2 < NT) ? t + 2 : 0;  // wrap: harmless dummy stage
    KTILE(0, tn1)
    KTILE(1, tn2)
  }
  asm volatile("s_waitcnt vmcnt(0)" ::: "memory");
}

// ---------------- GEMM1: h = gelu(gather(xb) @ W1t^T + b1) ----------------
__global__ __launch_bounds__(512, 2) void gemm1_kernel(const u16* __restrict__ xb,
                                                       const u16* __restrict__ W1t,
                                                       const float* __restrict__ b1,
                                                       const int* __restrict__ idx,
                                                       u16* __restrict__ hbuf) {
  // XCD-locality remap: expert e = p&7 -> XCD e (W1t[e] 4MB stays L2-resident)
  int p = blockIdx.x;
  int e = p & 7, slot = p >> 3;
  int bb = slot >> 4, xx = slot & 15;
  int tm = xx & 1, tn = xx >> 1;
  int be = bb * 8 + e;
  int t0 = tm * 256, n0 = tn * 256;
  int tid = threadIdx.x, lane = tid & 63, wid = tid >> 6;
  int wm = wid >> 2, wn = wid & 3;
  int cidx = lane & 15, kq = lane >> 4;
  __shared__ u16 As[2][2][8192];
  __shared__ u16 Bs[2][2][8192];

  // stage source pointers (pre-swizzled: kc = sl ^ (row&3))
  int srow = tid >> 2;
  int kc = (tid & 3) ^ (srow & 3);
  int tokA = idx[be * TK_ + t0 + srow];
  int tokB = idx[be * TK_ + t0 + 128 + srow];
  const u16* pa0 = xb + ((size_t)bb * S_ + tokA) * D_ + kc * 8;
  const u16* pa1 = xb + ((size_t)bb * S_ + tokB) * D_ + kc * 8;
  const u16* bsrc = W1t + (size_t)e * F_ * D_;
  const u16* pb0 = bsrc + (size_t)(n0 + srow) * D_ + kc * 8;
  const u16* pb1 = bsrc + (size_t)(n0 + 128 + srow) * D_ + kc * 8;

  // frag read offsets (swizzle lane-constant: row&3 == cidx&3)
  int swz = (kq ^ (cidx & 3)) * 8;
  int aoff[4], boff[4];
#pragma unroll
  for (int fi = 0; fi < 4; ++fi) {
    aoff[fi] = (wm * 128 + fi * 16 + cidx) * 32 + swz;
    boff[fi] = (wn * 64 + fi * 16 + cidx) * 32 + swz;
  }
  f32x4 acc[8][4];
#pragma unroll
  for (int f = 0; f < 8; ++f)
#pragma unroll
    for (int g = 0; g < 4; ++g) acc[f][g] = (f32x4){0.f, 0.f, 0.f, 0.f};

  kloop8(pa0, pa1, pb0, pb1, As, Bs, acc, D_ / 64, wid, aoff, boff);

  float bias[4];
#pragma unroll
  for (int g = 0; g < 4; ++g) bias[g] = b1[e * F_ + n0 + wn * 64 + g * 16 + cidx];
  size_t hbase = (size_t)be * TK_ * F_;
#pragma unroll
  for (int f = 0; f < 8; ++f) {
#pragma unroll
    for (int r = 0; r < 4; ++r) {
      int trow = t0 + wm * 128 + f * 16 + kq * 4 + r;
      size_t hb = hbase + (size_t)trow * F_ + n0 + wn * 64 + cidx;
#pragma unroll
      for (int g = 0; g < 4; ++g) {
        float v = acc[f][g][r] + bias[g];
        float gl = 0.5f * v * (1.0f + erff(v * 0.70710678118654752f));
        hbuf[hb + g * 16] = f2bf(gl);
      }
    }
  }
}

// ---------------- LayerNorm in place on h (wave per row) ----------------
__global__ __launch_bounds__(256) void norm_kernel(u16* __restrict__ hbuf,
                                                   const float* __restrict__ gamma,
                                                   const float* __restrict__ beta) {
  int row = blockIdx.x * 4 + (threadIdx.x >> 6);
  int lane = threadIdx.x & 63;
  int e = (row >> 9) & 7;
  u16* hr = hbuf + (size_t)row * F_;
  u16x8 raw[4];
  float sum = 0.f, ss = 0.f;
#pragma unroll
  for (int q = 0; q < 4; ++q) {
    raw[q] = *(const u16x8*)(hr + (q * 64 + lane) * 8);
#pragma unroll
    for (int j = 0; j < 8; ++j) {
      float v = b2f(raw[q][j]);
      sum += v;
      ss += v * v;
    }
  }
#pragma unroll
  for (int off = 32; off; off >>= 1) {
    sum += __shfl_down(sum, off);
    ss += __shfl_down(ss, off);
  }
  sum = __shfl(sum, 0);
  ss = __shfl(ss, 0);
  float mean = sum * (1.f / F_);
  float var = ss * (1.f / F_) - mean * mean;
  float rstd = rsqrtf(var + 1e-5f);
#pragma unroll
  for (int q = 0; q < 4; ++q) {
    int fb = (q * 64 + lane) * 8;
    const float* gr = gamma + (size_t)e * F_ + fb;
    const float* br = beta + (size_t)e * F_ + fb;
    float4 g0 = *(const float4*)gr, g1 = *(const float4*)(gr + 4);
    float4 t0 = *(const float4*)br, t1 = *(const float4*)(br + 4);
    float ga[8] = {g0.x, g0.y, g0.z, g0.w, g1.x, g1.y, g1.z, g1.w};
    float bt[8] = {t0.x, t0.y, t0.z, t0.w, t1.x, t1.y, t1.z, t1.w};
    u16x8 o;
#pragma unroll
    for (int j = 0; j < 8; ++j) {
      float v = (b2f(raw[q][j]) - mean) * rstd * ga[j] + bt[j];
      o[j] = f2bf(v);
    }
    *(u16x8*)(hr + (q * 64 + lane) * 8) = o;
  }
}

// ---------------- GEMM2: out = hn @ W2t^T + b2 -> weighted scatter-add ----------------
__global__ __launch_bounds__(512, 2) void gemm2_kernel(const u16* __restrict__ hbuf,
                                                       const u16* __restrict__ W2t,
                                                       const float* __restrict__ b2,
                                                       const int* __restrict__ idx,
                                                       const float* __restrict__ wts,
                                                       float* __restrict__ results) {
  int p = blockIdx.x;
  int e = p & 7, slot = p >> 3;
  int bb = slot >> 3, xx = slot & 7;
  int tm = xx >> 2, tn = xx & 3;
  int be = bb * 8 + e;
  int t0 = tm * 256, n0 = tn * 256;
  int tid = threadIdx.x, lane = tid & 63, wid = tid >> 6;
  int wm = wid >> 2, wn = wid & 3;
  int cidx = lane & 15, kq = lane >> 4;
  __shared__ u16 As[2][2][8192];
  __shared__ u16 Bs[2][2][8192];

  int srow = tid >> 2;
  int kc = (tid & 3) ^ (srow & 3);
  const u16* asrc = hbuf + (size_t)be * TK_ * F_;
  const u16* bsrc = W2t + (size_t)e * D_ * F_;
  const u16* pa0 = asrc + (size_t)(t0 + srow) * F_ + kc * 8;
  const u16* pa1 = asrc + (size_t)(t0 + 128 + srow) * F_ + kc * 8;
  const u16* pb0 = bsrc + (size_t)(n0 + srow) * F_ + kc * 8;
  const u16* pb1 = bsrc + (size_t)(n0 + 128 + srow) * F_ + kc * 8;

  int swz = (kq ^ (cidx & 3)) * 8;
  int aoff[4], boff[4];
#pragma unroll
  for (int fi = 0; fi < 4; ++fi) {
    aoff[fi] = (wm * 128 + fi * 16 + cidx) * 32 + swz;
    boff[fi] = (wn * 64 + fi * 16 + cidx) * 32 + swz;
  }
  f32x4 acc[8][4];
#pragma unroll
  for (int f = 0; f < 8; ++f)
#pragma unroll
    for (int g = 0; g < 4; ++g) acc[f][g] = (f32x4){0.f, 0.f, 0.f, 0.f};

  kloop8(pa0, pa1, pb0, pb1, As, Bs, acc, F_ / 64, wid, aoff, boff);

  float bias[4];
#pragma unroll
  for (int g = 0; g < 4; ++g) bias[g] = b2[e * D_ + n0 + wn * 64 + g * 16 + cidx];
#pragma unroll
  for (int f = 0; f < 8; ++f) {
#pragma unroll
    for (int r = 0; r < 4; ++r) {
      int trow = t0 + wm * 128 + f * 16 + kq * 4 + r;
      int tok = idx[be * TK_ + trow];
      float wv = wts[be * TK_ + trow];
      float* rrow = results + ((size_t)bb * S_ + tok) * D_ + n0 + wn * 64 + cidx;
#pragma unroll
      for (int g = 0; g < 4; ++g) {
        float val = wv * (acc[f][g][r] + bias[g]);
        unsafeAtomicAdd(rrow + g * 16, val);
      }
    }
  }
}

extern "C" void kernel_launch(void* const* d_in, const int* in_sizes, int n_in,
                              void* d_out, int out_size, void* d_ws, size_t ws_size,
                              hipStream_t stream) {
  const float* x = (const float*)d_in[0];
  const float* Wr = (const float*)d_in[1];
  const float* W1 = (const float*)d_in[2];
  const float* b1 = (const float*)d_in[3];
  const float* gamma = (const float*)d_in[4];
  const float* beta = (const float*)d_in[5];
  const float* W2 = (const float*)d_in[6];
  const float* b2 = (const float*)d_in[7];

  float* results = (float*)d_out;
  float* logits = results + (size_t)B_ * S_ * D_;

  char* ws = (char*)d_ws;
  const size_t OFF_IDX = 0;
  const size_t OFF_WTS = OFF_IDX + (size_t)B_ * E_ * TK_ * 4;
  const size_t OFF_R0 = OFF_WTS + (size_t)B_ * E_ * TK_ * 4;   // 32 MiB: xb, then W2t
  const size_t OFF_R1 = OFF_R0 + (size_t)E_ * D_ * F_ * 2;     // 32 MiB: W1t
  const size_t OFF_H = OFF_R1 + (size_t)E_ * D_ * F_ * 2;      // 64 MiB: h
  const size_t NEED = OFF_H + (size_t)B_ * E_ * TK_ * F_ * 2;
  if (ws_size < NEED) return;

  int* idx = (int*)(ws + OFF_IDX);
  float* wts = (float*)(ws + OFF_WTS);
  u16* xb = (u16*)(ws + OFF_R0);
  u16* W2t = (u16*)(ws + OFF_R0);
  u16* W1t = (u16*)(ws + OFF_R1);
  u16* hbuf = (u16*)(ws + OFF_H);

  hipMemsetAsync(d_out, 0, (size_t)B_ * S_ * D_ * sizeof(float), stream);

  router_kernel<<<dim3(B_ * S_ / 4), 256, 0, stream>>>(x, Wr, logits);
  topk_kernel<<<dim3(B_ * E_), 1024, 0, stream>>>(logits, idx, wts);
  cvt_bf16_kernel<<<dim3((B_ * S_ * D_) / 2048), 256, 0, stream>>>(x, xb);
  transpose_cvt_kernel<<<dim3(D_ / 32, F_ / 32, E_), 256, 0, stream>>>(W1, W1t, D_, F_);
  gemm1_kernel<<<dim3(512), 512, 0, stream>>>(xb, W1t, b1, idx, hbuf);
  // W2t overwrites xb region only after gemm1 completed (in-order stream)
  transpose_cvt_kernel<<<dim3(F_ / 32, D_ / 32, E_), 256, 0, stream>>>(W2, W2t, F_, D_);
  norm_kernel<<<dim3(B_ * E_ * TK_ / 4), 256, 0, stream>>>(hbuf, gamma, beta);
  gemm2_kernel<<<dim3(256), 512, 0, stream>>>(hbuf, W2t, b2, idx, wts, results);
}

// Round 4
// 400.282 us; speedup vs baseline: 1.2426x; 1.1169x over previous
//
#include <hip/hip_runtime.h>
#include <hip/hip_bf16.h>

#define B_ 4
#define S_ 4096
#define D_ 1024
#define E_ 8
#define F_ 2048
#define TK_ 512

typedef unsigned short u16;
typedef unsigned int u32;
typedef u16 u16x8 __attribute__((ext_vector_type(8)));
typedef short s16x8 __attribute__((ext_vector_type(8)));
typedef float f32x4 __attribute__((ext_vector_type(4)));

__device__ __forceinline__ u16 f2bf(float f) {
  u32 u = __builtin_bit_cast(u32, f);
  u32 r = (u + 0x7fffu + ((u >> 16) & 1u)) >> 16;
  return (u16)r;
}
__device__ __forceinline__ float b2f(u16 h) {
  return __builtin_bit_cast(float, ((u32)h) << 16);
}
__device__ __forceinline__ void gload16(const u16* g, const u16* l) {
  __builtin_amdgcn_global_load_lds((const __attribute__((address_space(1))) void*)g,
                                   (__attribute__((address_space(3))) void*)l, 16, 0, 0);
}
__device__ __forceinline__ f32x4 mfma_bf16(s16x8 a, s16x8 b, f32x4 c) {
  return __builtin_amdgcn_mfma_f32_16x16x32_bf16(a, b, c, 0, 0, 0);
}

// ---------------- router: logits = x @ Wr ----------------
__global__ __launch_bounds__(256) void router_kernel(const float* __restrict__ x,
                                                     const float* __restrict__ Wr,
                                                     float* __restrict__ logits) {
  __shared__ float wr[D_ * E_];
  for (int i = threadIdx.x; i < D_ * E_; i += 256) wr[i] = Wr[i];
  __syncthreads();
  int lane = threadIdx.x & 63;
  int wid = threadIdx.x >> 6;
  int token = blockIdx.x * 4 + wid;
  const float* xr = x + (size_t)token * D_;
  float acc[E_];
#pragma unroll
  for (int e = 0; e < E_; ++e) acc[e] = 0.f;
#pragma unroll
  for (int q = 0; q < 4; ++q) {
    int d0 = q * 256 + lane * 4;
    float4 v = *(const float4*)(xr + d0);
    float xv[4] = {v.x, v.y, v.z, v.w};
    const float* w0 = &wr[d0 * E_];
#pragma unroll
    for (int j = 0; j < 4; ++j) {
#pragma unroll
      for (int e = 0; e < E_; ++e) acc[e] += xv[j] * w0[j * E_ + e];
    }
  }
#pragma unroll
  for (int e = 0; e < E_; ++e) {
#pragma unroll
    for (int off = 32; off; off >>= 1) acc[e] += __shfl_down(acc[e], off);
  }
  if (lane == 0) {
    float4 o0 = make_float4(acc[0], acc[1], acc[2], acc[3]);
    float4 o1 = make_float4(acc[4], acc[5], acc[6], acc[7]);
    *(float4*)(logits + (size_t)token * E_) = o0;
    *(float4*)(logits + (size_t)token * E_ + 4) = o1;
  }
}

// ---------------- top-k per (b,e): bitonic sort of 4096 probs ----------------
__global__ __launch_bounds__(1024) void topk_kernel(const float* __restrict__ logits,
                                                    int* __restrict__ idx,
                                                    float* __restrict__ wts) {
  int be = blockIdx.x, b = be >> 3, e = be & 7;
  __shared__ float pv[S_];
  __shared__ u16 pi[S_];
  const float* lg = logits + (size_t)b * S_ * E_;
  for (int s = threadIdx.x; s < S_; s += 1024) {
    float4 l0 = *(const float4*)(lg + (size_t)s * E_);
    float4 l1 = *(const float4*)(lg + (size_t)s * E_ + 4);
    float la[8] = {l0.x, l0.y, l0.z, l0.w, l1.x, l1.y, l1.z, l1.w};
    float mx = la[0];
#pragma unroll
    for (int t = 1; t < 8; ++t) mx = fmaxf(mx, la[t]);
    float sum = 0.f;
#pragma unroll
    for (int t = 0; t < 8; ++t) sum += expf(la[t] - mx);
    float p = expf(la[e] - mx) / sum;
    pv[s] = p;
    pi[s] = (u16)s;
  }
  __syncthreads();
  for (int k = 2; k <= S_; k <<= 1) {
    for (int j = k >> 1; j > 0; j >>= 1) {
      for (int i = threadIdx.x; i < S_; i += 1024) {
        int l = i ^ j;
        if (l > i) {
          float va = pv[i], vb = pv[l];
          u16 ia = pi[i], ib = pi[l];
          bool ok = (va > vb) || (va == vb && ia < ib);
          bool up = ((i & k) == 0);
          if (up ? !ok : ok) {
            pv[i] = vb; pv[l] = va;
            pi[i] = ib; pi[l] = ia;
          }
        }
      }
      __syncthreads();
    }
  }
  for (int t = threadIdx.x; t < TK_; t += 1024) {
    idx[be * TK_ + t] = (int)pi[t];
    wts[be * TK_ + t] = pv[t];
  }
}

// ---------------- x f32 -> bf16 ----------------
__global__ __launch_bounds__(256) void cvt_bf16_kernel(const float* __restrict__ src,
                                                       u16* __restrict__ dst) {
  size_t i = ((size_t)blockIdx.x * 256 + threadIdx.x) * 8;
  float4 v0 = *(const float4*)(src + i);
  float4 v1 = *(const float4*)(src + i + 4);
  u16x8 o;
  o[0] = f2bf(v0.x); o[1] = f2bf(v0.y); o[2] = f2bf(v0.z); o[3] = f2bf(v0.w);
  o[4] = f2bf(v1.x); o[5] = f2bf(v1.y); o[6] = f2bf(v1.z); o[7] = f2bf(v1.w);
  *(u16x8*)(dst + i) = o;
}

// ---------------- transpose + f32->bf16: dst[c][r] = src[r][c] per expert ----------------
__global__ __launch_bounds__(256) void transpose_cvt_kernel(const float* __restrict__ src,
                                                            u16* __restrict__ dst,
                                                            int R, int C) {
  __shared__ float tile[32][33];
  int z = blockIdx.z;
  const float* s = src + (size_t)z * R * C;
  u16* d = dst + (size_t)z * R * C;
  int r0 = blockIdx.x * 32, c0 = blockIdx.y * 32;
  int xx = threadIdx.x & 31, yy = threadIdx.x >> 5;
#pragma unroll
  for (int q = 0; q < 4; ++q)
    tile[yy + q * 8][xx] = s[(size_t)(r0 + yy + q * 8) * C + c0 + xx];
  __syncthreads();
#pragma unroll
  for (int q = 0; q < 4; ++q)
    d[(size_t)(c0 + yy + q * 8) * R + r0 + xx] = f2bf(tile[xx][yy + q * 8]);
}

// =====================================================================
// m97-structure K-loop: 128x128 tile, BK=64, 4 waves, single-buffer LDS
// (32 KB -> ~3 blocks/CU with ~150 regs). Per K-step: 8x gload16 ->
// vmcnt(0)+barrier -> 16 ds_read_b128 + 32 MFMA -> barrier. Latency
// hidden by cross-block TLP (m114). G4 swizzle slot^=(row&7), both sides.
// =====================================================================
__device__ __forceinline__ void kloop97(const u16* const pa[4], const u16* const pb[4],
                                        u16* As, u16* Bs, f32x4 acc[4][4], int NT,
                                        int wid, const int aoff[4], const int boff[4],
                                        int sk0, int sk1) {
  int ldst = wid * 512;
  for (int t = 0; t < NT; ++t) {
    int k0 = t * 64;
#pragma unroll
    for (int q = 0; q < 4; ++q) gload16(pa[q] + k0, As + q * 2048 + ldst);
#pragma unroll
    for (int q = 0; q < 4; ++q) gload16(pb[q] + k0, Bs + q * 2048 + ldst);
    asm volatile("s_waitcnt vmcnt(0)" ::: "memory");
    __builtin_amdgcn_s_barrier();
    s16x8 aF[4], bF[4];
#pragma unroll
    for (int kk = 0; kk < 2; ++kk) {
      int sk = kk ? sk1 : sk0;
#pragma unroll
      for (int f = 0; f < 4; ++f) aF[f] = *(const s16x8*)&As[aoff[f] + sk];
#pragma unroll
      for (int g = 0; g < 4; ++g) bF[g] = *(const s16x8*)&Bs[boff[g] + sk];
      __builtin_amdgcn_s_setprio(1);
#pragma unroll
      for (int f = 0; f < 4; ++f)
#pragma unroll
        for (int g = 0; g < 4; ++g) acc[f][g] = mfma_bf16(aF[f], bF[g], acc[f][g]);
      __builtin_amdgcn_s_setprio(0);
    }
    __builtin_amdgcn_s_barrier();
  }
}

// ---------------- GEMM1: h = gelu(gather(xb) @ W1t^T + b1) ----------------
__global__ __launch_bounds__(256, 2) void gemm1_kernel(const u16* __restrict__ xb,
                                                       const u16* __restrict__ W1t,
                                                       const float* __restrict__ b1,
                                                       const int* __restrict__ idx,
                                                       u16* __restrict__ hbuf) {
  // XCD pin: expert e = p&7. slot order: tm inner (B-panel stays L2-hot).
  int p = blockIdx.x;
  int e = p & 7, slot = p >> 3;          // 0..255
  int tm = slot & 3, bb = (slot >> 2) & 3, tn = slot >> 4;  // tn 0..15
  int be = bb * 8 + e;
  int t0 = tm * 128, n0 = tn * 128;
  int tid = threadIdx.x, lane = tid & 63, wid = tid >> 6;
  int wm = wid >> 1, wn = wid & 1;
  int cidx = lane & 15, kq = lane >> 4;
  __shared__ u16 As[128 * 64];
  __shared__ u16 Bs[128 * 64];

  // staging pointers: thread covers row q*32 + (tid>>3), chunk kc (pre-swizzled)
  int srow = tid >> 3;                    // 0..31
  int kc = (tid & 7) ^ (srow & 7);        // inverse swizzle on global source
  const u16* pa[4];
  const u16* pb[4];
  const u16* bsrc = W1t + (size_t)e * F_ * D_;
#pragma unroll
  for (int q = 0; q < 4; ++q) {
    int tok = idx[be * TK_ + t0 + q * 32 + srow];
    pa[q] = xb + ((size_t)bb * S_ + tok) * D_ + kc * 8;
    pb[q] = bsrc + (size_t)(n0 + q * 32 + srow) * D_ + kc * 8;
  }
  // frag read offsets: row part + swizzled k-slot (row&7 == cidx&7 here)
  int aoff[4], boff[4];
#pragma unroll
  for (int f = 0; f < 4; ++f) {
    aoff[f] = (wm * 64 + f * 16 + cidx) * 64;
    boff[f] = (wn * 64 + f * 16 + cidx) * 64;
  }
  int sk0 = (kq ^ (cidx & 7)) * 8;
  int sk1 = ((4 + kq) ^ (cidx & 7)) * 8;

  f32x4 acc[4][4];
#pragma unroll
  for (int f = 0; f < 4; ++f)
#pragma unroll
    for (int g = 0; g < 4; ++g) acc[f][g] = (f32x4){0.f, 0.f, 0.f, 0.f};

  kloop97(pa, pb, As, Bs, acc, D_ / 64, wid, aoff, boff, sk0, sk1);

  float bias[4];
#pragma unroll
  for (int g = 0; g < 4; ++g) bias[g] = b1[e * F_ + n0 + wn * 64 + g * 16 + cidx];
  size_t hbase = (size_t)be * TK_ * F_;
#pragma unroll
  for (int f = 0; f < 4; ++f) {
#pragma unroll
    for (int r = 0; r < 4; ++r) {
      int trow = t0 + wm * 64 + f * 16 + kq * 4 + r;
      size_t hb = hbase + (size_t)trow * F_ + n0 + wn * 64 + cidx;
#pragma unroll
      for (int g = 0; g < 4; ++g) {
        float v = acc[f][g][r] + bias[g];
        float gl = 0.5f * v * (1.0f + erff(v * 0.70710678118654752f));
        hbuf[hb + g * 16] = f2bf(gl);
      }
    }
  }
}

// ---------------- LayerNorm in place on h (wave per row) ----------------
__global__ __launch_bounds__(256) void norm_kernel(u16* __restrict__ hbuf,
                                                   const float* __restrict__ gamma,
                                                   const float* __restrict__ beta) {
  int row = blockIdx.x * 4 + (threadIdx.x >> 6);
  int lane = threadIdx.x & 63;
  int e = (row >> 9) & 7;
  u16* hr = hbuf + (size_t)row * F_;
  u16x8 raw[4];
  float sum = 0.f, ss = 0.f;
#pragma unroll
  for (int q = 0; q < 4; ++q) {
    raw[q] = *(const u16x8*)(hr + (q * 64 + lane) * 8);
#pragma unroll
    for (int j = 0; j < 8; ++j) {
      float v = b2f(raw[q][j]);
      sum += v;
      ss += v * v;
    }
  }
#pragma unroll
  for (int off = 32; off; off >>= 1) {
    sum += __shfl_down(sum, off);
    ss += __shfl_down(ss, off);
  }
  sum = __shfl(sum, 0);
  ss = __shfl(ss, 0);
  float mean = sum * (1.f / F_);
  float var = ss * (1.f / F_) - mean * mean;
  float rstd = rsqrtf(var + 1e-5f);
#pragma unroll
  for (int q = 0; q < 4; ++q) {
    int fb = (q * 64 + lane) * 8;
    const float* gr = gamma + (size_t)e * F_ + fb;
    const float* br = beta + (size_t)e * F_ + fb;
    float4 g0 = *(const float4*)gr, g1 = *(const float4*)(gr + 4);
    float4 t0 = *(const float4*)br, t1 = *(const float4*)(br + 4);
    float ga[8] = {g0.x, g0.y, g0.z, g0.w, g1.x, g1.y, g1.z, g1.w};
    float bt[8] = {t0.x, t0.y, t0.z, t0.w, t1.x, t1.y, t1.z, t1.w};
    u16x8 o;
#pragma unroll
    for (int j = 0; j < 8; ++j) {
      float v = (b2f(raw[q][j]) - mean) * rstd * ga[j] + bt[j];
      o[j] = f2bf(v);
    }
    *(u16x8*)(hr + (q * 64 + lane) * 8) = o;
  }
}

// ---------------- GEMM2: out = hn @ W2t^T + b2 -> weighted scatter-add ----------------
__global__ __launch_bounds__(256, 2) void gemm2_kernel(const u16* __restrict__ hbuf,
                                                       const u16* __restrict__ W2t,
                                                       const float* __restrict__ b2,
                                                       const int* __restrict__ idx,
                                                       const float* __restrict__ wts,
                                                       float* __restrict__ results) {
  // XCD pin; slot order: tn inner (A-tile stays hot; W2t expert = 4MB = L2).
  int p = blockIdx.x;
  int e = p & 7, slot = p >> 3;          // 0..127
  int tn = slot & 7, tm = (slot >> 3) & 3, bb = slot >> 5;
  int be = bb * 8 + e;
  int t0 = tm * 128, n0 = tn * 128;
  int tid = threadIdx.x, lane = tid & 63, wid = tid >> 6;
  int wm = wid >> 1, wn = wid & 1;
  int cidx = lane & 15, kq = lane >> 4;
  __shared__ u16 As[128 * 64];
  __shared__ u16 Bs[128 * 64];

  int srow = tid >> 3;
  int kc = (tid & 7) ^ (srow & 7);
  const u16* pa[4];
  const u16* pb[4];
  const u16* asrc = hbuf + (size_t)be * TK_ * F_;
  const u16* bsrc = W2t + (size_t)e * D_ * F_;
#pragma unroll
  for (int q = 0; q < 4; ++q) {
    pa[q] = asrc + (size_t)(t0 + q * 32 + srow) * F_ + kc * 8;
    pb[q] = bsrc + (size_t)(n0 + q * 32 + srow) * F_ + kc * 8;
  }
  int aoff[4], boff[4];
#pragma unroll
  for (int f = 0; f < 4; ++f) {
    aoff[f] = (wm * 64 + f * 16 + cidx) * 64;
    boff[f] = (wn * 64 + f * 16 + cidx) * 64;
  }
  int sk0 = (kq ^ (cidx & 7)) * 8;
  int sk1 = ((4 + kq) ^ (cidx & 7)) * 8;

  f32x4 acc[4][4];
#pragma unroll
  for (int f = 0; f < 4; ++f)
#pragma unroll
    for (int g = 0; g < 4; ++g) acc[f][g] = (f32x4){0.f, 0.f, 0.f, 0.f};

  kloop97(pa, pb, As, Bs, acc, F_ / 64, wid, aoff, boff, sk0, sk1);

  float bias[4];
#pragma unroll
  for (int g = 0; g < 4; ++g) bias[g] = b2[e * D_ + n0 + wn * 64 + g * 16 + cidx];
#pragma unroll
  for (int f = 0; f < 4; ++f) {
#pragma unroll
    for (int r = 0; r < 4; ++r) {
      int trow = t0 + wm * 64 + f * 16 + kq * 4 + r;
      int tok = idx[be * TK_ + trow];
      float wv = wts[be * TK_ + trow];
      float* rrow = results + ((size_t)bb * S_ + tok) * D_ + n0 + wn * 64 + cidx;
#pragma unroll
      for (int g = 0; g < 4; ++g) {
        float val = wv * (acc[f][g][r] + bias[g]);
        unsafeAtomicAdd(rrow + g * 16, val);
      }
    }
  }
}

extern "C" void kernel_launch(void* const* d_in, const int* in_sizes, int n_in,
                              void* d_out, int out_size, void* d_ws, size_t ws_size,
                              hipStream_t stream) {
  const float* x = (const float*)d_in[0];
  const float* Wr = (const float*)d_in[1];
  const float* W1 = (const float*)d_in[2];
  const float* b1 = (const float*)d_in[3];
  const float* gamma = (const float*)d_in[4];
  const float* beta = (const float*)d_in[5];
  const float* W2 = (const float*)d_in[6];
  const float* b2 = (const float*)d_in[7];

  float* results = (float*)d_out;
  float* logits = results + (size_t)B_ * S_ * D_;

  char* ws = (char*)d_ws;
  const size_t OFF_IDX = 0;
  const size_t OFF_WTS = OFF_IDX + (size_t)B_ * E_ * TK_ * 4;
  const size_t OFF_R0 = OFF_WTS + (size_t)B_ * E_ * TK_ * 4;   // 32 MiB: xb, then W2t
  const size_t OFF_R1 = OFF_R0 + (size_t)E_ * D_ * F_ * 2;     // 32 MiB: W1t
  const size_t OFF_H = OFF_R1 + (size_t)E_ * D_ * F_ * 2;      // 64 MiB: h
  const size_t NEED = OFF_H + (size_t)B_ * E_ * TK_ * F_ * 2;
  if (ws_size < NEED) return;

  int* idx = (int*)(ws + OFF_IDX);
  float* wts = (float*)(ws + OFF_WTS);
  u16* xb = (u16*)(ws + OFF_R0);
  u16* W2t = (u16*)(ws + OFF_R0);
  u16* W1t = (u16*)(ws + OFF_R1);
  u16* hbuf = (u16*)(ws + OFF_H);

  hipMemsetAsync(d_out, 0, (size_t)B_ * S_ * D_ * sizeof(float), stream);

  router_kernel<<<dim3(B_ * S_ / 4), 256, 0, stream>>>(x, Wr, logits);
  topk_kernel<<<dim3(B_ * E_), 1024, 0, stream>>>(logits, idx, wts);
  cvt_bf16_kernel<<<dim3((B_ * S_ * D_) / 2048), 256, 0, stream>>>(x, xb);
  transpose_cvt_kernel<<<dim3(D_ / 32, F_ / 32, E_), 256, 0, stream>>>(W1, W1t, D_, F_);
  gemm1_kernel<<<dim3(2048), 256, 0, stream>>>(xb, W1t, b1, idx, hbuf);
  // W2t overwrites xb region only after gemm1 completed (in-order stream)
  transpose_cvt_kernel<<<dim3(F_ / 32, D_ / 32, E_), 256, 0, stream>>>(W2, W2t, F_, D_);
  norm_kernel<<<dim3(B_ * E_ * TK_ / 4), 256, 0, stream>>>(hbuf, gamma, beta);
  gemm2_kernel<<<dim3(1024), 256, 0, stream>>>(hbuf, W2t, b2, idx, wts, results);
}

// Round 5
// 322.469 us; speedup vs baseline: 1.5424x; 1.2413x over previous
//
#include <hip/hip_runtime.h>
#include <hip/hip_bf16.h>

#define B_ 4
#define S_ 4096
#define D_ 1024
#define E_ 8
#define F_ 2048
#define TK_ 512

typedef unsigned short u16;
typedef unsigned int u32;
typedef u16 u16x4 __attribute__((ext_vector_type(4)));
typedef u16 u16x8 __attribute__((ext_vector_type(8)));
typedef short s16x8 __attribute__((ext_vector_type(8)));
typedef float f32x4 __attribute__((ext_vector_type(4)));

__device__ __forceinline__ u16 f2bf(float f) {
  u32 u = __builtin_bit_cast(u32, f);
  u32 r = (u + 0x7fffu + ((u >> 16) & 1u)) >> 16;
  return (u16)r;
}
__device__ __forceinline__ float b2f(u16 h) {
  return __builtin_bit_cast(float, ((u32)h) << 16);
}
__device__ __forceinline__ void gload16(const u16* g, const u16* l) {
  __builtin_amdgcn_global_load_lds((const __attribute__((address_space(1))) void*)g,
                                   (__attribute__((address_space(3))) void*)l, 16, 0, 0);
}
__device__ __forceinline__ f32x4 mfma_bf16(s16x8 a, s16x8 b, f32x4 c) {
  return __builtin_amdgcn_mfma_f32_16x16x32_bf16(a, b, c, 0, 0, 0);
}

// ---------------- fused: router logits + x->bf16 + zero(results) ----------------
__global__ __launch_bounds__(256) void rc_kernel(const float* __restrict__ x,
                                                 const float* __restrict__ Wr,
                                                 float* __restrict__ logits,
                                                 u16* __restrict__ xb,
                                                 float* __restrict__ results) {
  __shared__ float wr[D_ * E_];
  for (int i = threadIdx.x; i < D_ * E_; i += 256) wr[i] = Wr[i];
  __syncthreads();
  int lane = threadIdx.x & 63;
  int wid = threadIdx.x >> 6;
  int token = blockIdx.x * 4 + wid;
  const float* xr = x + (size_t)token * D_;
  u16* xo = xb + (size_t)token * D_;
  float* ro = results + (size_t)token * D_;
  float acc[E_];
#pragma unroll
  for (int e = 0; e < E_; ++e) acc[e] = 0.f;
#pragma unroll
  for (int q = 0; q < 4; ++q) {
    int d0 = q * 256 + lane * 4;
    float4 v = *(const float4*)(xr + d0);
    u16x4 st;
    st[0] = f2bf(v.x); st[1] = f2bf(v.y); st[2] = f2bf(v.z); st[3] = f2bf(v.w);
    *(u16x4*)(xo + d0) = st;
    *(float4*)(ro + d0) = make_float4(0.f, 0.f, 0.f, 0.f);
    float xv[4] = {v.x, v.y, v.z, v.w};
    const float* w0 = &wr[d0 * E_];
#pragma unroll
    for (int j = 0; j < 4; ++j) {
#pragma unroll
      for (int e = 0; e < E_; ++e) acc[e] += xv[j] * w0[j * E_ + e];
    }
  }
#pragma unroll
  for (int e = 0; e < E_; ++e) {
#pragma unroll
    for (int off = 32; off; off >>= 1) acc[e] += __shfl_down(acc[e], off);
  }
  if (lane == 0) {
    float4 o0 = make_float4(acc[0], acc[1], acc[2], acc[3]);
    float4 o1 = make_float4(acc[4], acc[5], acc[6], acc[7]);
    *(float4*)(logits + (size_t)token * E_) = o0;
    *(float4*)(logits + (size_t)token * E_ + 4) = o1;
  }
}

// ---------------- top-k per (b,e): exact 3-level radix-histogram select ----------------
// Set + weights only (scatter-add is order-invariant); ties at the threshold
// value taken by LOWEST index (matches jax.lax.top_k semantics).
__device__ __forceinline__ void suffix_scan(u32* h, int n, int tid) {
  for (int d = 1; d < n; d <<= 1) {
    u32 v[2];
    int c = 0;
    for (int i = tid; i < n; i += 1024) v[c++] = (i + d < n) ? h[i + d] : 0;
    __syncthreads();
    c = 0;
    for (int i = tid; i < n; i += 1024) h[i] += v[c++];
    __syncthreads();
  }
}

__global__ __launch_bounds__(1024) void topk_kernel(const float* __restrict__ logits,
                                                    int* __restrict__ idx,
                                                    float* __restrict__ wts) {
  int be = blockIdx.x, b = be >> 3, e = be & 7;
  __shared__ u32 keys[S_];
  __shared__ u32 hist[2048];
  __shared__ u32 tcnt[1024];
  __shared__ u32 sb, sneed, scnt;
  int tid = threadIdx.x;
  const float* lg = logits + (size_t)b * S_ * E_;
  for (int s = tid; s < S_; s += 1024) {
    float4 l0 = *(const float4*)(lg + (size_t)s * E_);
    float4 l1 = *(const float4*)(lg + (size_t)s * E_ + 4);
    float la[8] = {l0.x, l0.y, l0.z, l0.w, l1.x, l1.y, l1.z, l1.w};
    float mx = la[0];
#pragma unroll
    for (int t = 1; t < 8; ++t) mx = fmaxf(mx, la[t]);
    float sum = 0.f;
#pragma unroll
    for (int t = 0; t < 8; ++t) sum += expf(la[t] - mx);
    float p = expf(la[e] - mx) / sum;
    keys[s] = __builtin_bit_cast(u32, p);  // p>0: u32 order == float order
  }
  if (tid == 0) scnt = 0;

  // ---- level 1: bits 31:21 ----
  hist[tid] = 0; hist[tid + 1024] = 0;
  __syncthreads();
  for (int s = tid; s < S_; s += 1024) atomicAdd(&hist[keys[s] >> 21], 1u);
  __syncthreads();
  suffix_scan(hist, 2048, tid);
  for (int i = tid; i < 2048; i += 1024) {
    u32 nxt = (i + 1 < 2048) ? hist[i + 1] : 0;
    if (hist[i] >= (u32)TK_ && nxt < (u32)TK_) { sb = (u32)i; sneed = TK_ - nxt; }
  }
  __syncthreads();
  u32 b1 = sb, need1 = sneed;
  __syncthreads();

  // ---- level 2: bits 20:10 within bin b1 ----
  hist[tid] = 0; hist[tid + 1024] = 0;
  __syncthreads();
  for (int s = tid; s < S_; s += 1024)
    if ((keys[s] >> 21) == b1) atomicAdd(&hist[(keys[s] >> 10) & 2047u], 1u);
  __syncthreads();
  suffix_scan(hist, 2048, tid);
  for (int i = tid; i < 2048; i += 1024) {
    u32 nxt = (i + 1 < 2048) ? hist[i + 1] : 0;
    if (hist[i] >= need1 && nxt < need1) { sb = (u32)i; sneed = need1 - nxt; }
  }
  __syncthreads();
  u32 p2 = (b1 << 11) | sb, need2 = sneed;
  __syncthreads();

  // ---- level 3: bits 9:0 within prefix p2 ----
  if (tid < 1024) hist[tid] = 0;
  __syncthreads();
  for (int s = tid; s < S_; s += 1024)
    if ((keys[s] >> 10) == p2) atomicAdd(&hist[keys[s] & 1023u], 1u);
  __syncthreads();
  suffix_scan(hist, 1024, tid);
  for (int i = tid; i < 1024; i += 1024) {
    u32 nxt = (i + 1 < 1024) ? hist[i + 1] : 0;
    if (hist[i] >= need2 && nxt < need2) { sb = (u32)i; sneed = need2 - nxt; }
  }
  __syncthreads();
  u32 T = (p2 << 10) | sb;
  u32 needT = sneed;

  // ---- write: strictly greater than T ----
  for (int s = tid; s < S_; s += 1024) {
    if (keys[s] > T) {
      u32 p = atomicAdd(&scnt, 1u);
      idx[be * TK_ + p] = s;
      wts[be * TK_ + p] = __builtin_bit_cast(float, keys[s]);
    }
  }
  // ---- ties == T by lowest index: rank via block scan (contiguous chunks) ----
  u32 myc = 0;
#pragma unroll
  for (int j = 0; j < 4; ++j) myc += (keys[tid * 4 + j] == T) ? 1u : 0u;
  tcnt[tid] = myc;
  __syncthreads();
  for (int d = 1; d < 1024; d <<= 1) {
    u32 v = (tid >= d) ? tcnt[tid - d] : 0;
    __syncthreads();
    tcnt[tid] += v;
    __syncthreads();
  }
  u32 rank = tcnt[tid] - myc;
#pragma unroll
  for (int j = 0; j < 4; ++j) {
    int s = tid * 4 + j;
    if (keys[s] == T) {
      if (rank < needT) {
        u32 p = atomicAdd(&scnt, 1u);
        idx[be * TK_ + p] = s;
        wts[be * TK_ + p] = __builtin_bit_cast(float, T);
      }
      rank++;
    }
  }
}

// ---------------- transpose + f32->bf16 (+optional row-scale, +optional beta-col-sums) ----------------
__global__ __launch_bounds__(256) void transpose_cvt_kernel(const float* __restrict__ src,
                                                            u16* __restrict__ dst,
                                                            int R, int C,
                                                            const float* __restrict__ scale,
                                                            const float* __restrict__ beta,
                                                            float* __restrict__ Bd) {
  __shared__ float tile[32][33];
  int z = blockIdx.z;
  const float* s = src + (size_t)z * R * C;
  u16* d = dst + (size_t)z * R * C;
  int r0 = blockIdx.x * 32, c0 = blockIdx.y * 32;
  int xx = threadIdx.x & 31, yy = threadIdx.x >> 5;
#pragma unroll
  for (int q = 0; q < 4; ++q)
    tile[yy + q * 8][xx] = s[(size_t)(r0 + yy + q * 8) * C + c0 + xx];
  __syncthreads();
  float sc = scale ? scale[(size_t)z * R + r0 + xx] : 1.f;
#pragma unroll
  for (int q = 0; q < 4; ++q)
    d[(size_t)(c0 + yy + q * 8) * R + r0 + xx] = f2bf(sc * tile[xx][yy + q * 8]);
  if (Bd != nullptr) {
    __syncthreads();
    if (threadIdx.x < 32) {
      float sm = 0.f;
      const float* br = beta + (size_t)z * R + r0;
#pragma unroll
      for (int f = 0; f < 32; ++f) sm += br[f] * tile[f][threadIdx.x];
      unsafeAtomicAdd(&Bd[(size_t)z * C + c0 + threadIdx.x], sm);
    }
  }
}

// ---------------- GEMV: G[e][d] = sum_f W2g[e][d][f]  (gamma already folded) ----------------
__global__ __launch_bounds__(256) void gemv_g_kernel(const u16* __restrict__ W2g,
                                                     float* __restrict__ G) {
  int row = blockIdx.x * 4 + (threadIdx.x >> 6);  // e*D + d
  int lane = threadIdx.x & 63;
  const u16* wr = W2g + (size_t)row * F_;
  float s = 0.f;
#pragma unroll
  for (int j = 0; j < 4; ++j) {
    u16x8 v = *(const u16x8*)(wr + (j * 64 + lane) * 8);
#pragma unroll
    for (int t = 0; t < 8; ++t) s += b2f(v[t]);
  }
#pragma unroll
  for (int off = 32; off; off >>= 1) s += __shfl_down(s, off);
  if (lane == 0) G[row] = s;
}

// =====================================================================
// m97-structure K-loop (verified R4): 128x128 tile, BK=64, 4 waves,
// single-buffer 32KB LDS, cross-block TLP hides the vmcnt(0) drain.
// G4 swizzle slot^=(row&7), both sides. DO NOT restructure (R3 lesson).
// =====================================================================
__device__ __forceinline__ void kloop97(const u16* const pa[4], const u16* const pb[4],
                                        u16* As, u16* Bs, f32x4 acc[4][4], int NT,
                                        int wid, const int aoff[4], const int boff[4],
                                        int sk0, int sk1) {
  int ldst = wid * 512;
  for (int t = 0; t < NT; ++t) {
    int k0 = t * 64;
#pragma unroll
    for (int q = 0; q < 4; ++q) gload16(pa[q] + k0, As + q * 2048 + ldst);
#pragma unroll
    for (int q = 0; q < 4; ++q) gload16(pb[q] + k0, Bs + q * 2048 + ldst);
    asm volatile("s_waitcnt vmcnt(0)" ::: "memory");
    __builtin_amdgcn_s_barrier();
    s16x8 aF[4], bF[4];
#pragma unroll
    for (int kk = 0; kk < 2; ++kk) {
      int sk = kk ? sk1 : sk0;
#pragma unroll
      for (int f = 0; f < 4; ++f) aF[f] = *(const s16x8*)&As[aoff[f] + sk];
#pragma unroll
      for (int g = 0; g < 4; ++g) bF[g] = *(const s16x8*)&Bs[boff[g] + sk];
      __builtin_amdgcn_s_setprio(1);
#pragma unroll
      for (int f = 0; f < 4; ++f)
#pragma unroll
        for (int g = 0; g < 4; ++g) acc[f][g] = mfma_bf16(aF[f], bF[g], acc[f][g]);
      __builtin_amdgcn_s_setprio(0);
    }
    __builtin_amdgcn_s_barrier();
  }
}

// ---------------- GEMM1: h = gelu(gather(xb) @ W1t^T + b1) + per-row LN stats ----------------
__global__ __launch_bounds__(256, 2) void gemm1_kernel(const u16* __restrict__ xb,
                                                       const u16* __restrict__ W1t,
                                                       const float* __restrict__ b1,
                                                       const int* __restrict__ idx,
                                                       u16* __restrict__ hbuf,
                                                       float2* __restrict__ stats2) {
  int p = blockIdx.x;
  int e = p & 7, slot = p >> 3;
  int tm = slot & 3, bb = (slot >> 2) & 3, tn = slot >> 4;
  int be = bb * 8 + e;
  int t0 = tm * 128, n0 = tn * 128;
  int tid = threadIdx.x, lane = tid & 63, wid = tid >> 6;
  int wm = wid >> 1, wn = wid & 1;
  int cidx = lane & 15, kq = lane >> 4;
  __shared__ u16 As[128 * 64];
  __shared__ u16 Bs[128 * 64];
  __shared__ float2 sm[128][2];

  int srow = tid >> 3;
  int kc = (tid & 7) ^ (srow & 7);
  const u16* pa[4];
  const u16* pb[4];
  const u16* bsrc = W1t + (size_t)e * F_ * D_;
#pragma unroll
  for (int q = 0; q < 4; ++q) {
    int tok = idx[be * TK_ + t0 + q * 32 + srow];
    pa[q] = xb + ((size_t)bb * S_ + tok) * D_ + kc * 8;
    pb[q] = bsrc + (size_t)(n0 + q * 32 + srow) * D_ + kc * 8;
  }
  int aoff[4], boff[4];
#pragma unroll
  for (int f = 0; f < 4; ++f) {
    aoff[f] = (wm * 64 + f * 16 + cidx) * 64;
    boff[f] = (wn * 64 + f * 16 + cidx) * 64;
  }
  int sk0 = (kq ^ (cidx & 7)) * 8;
  int sk1 = ((4 + kq) ^ (cidx & 7)) * 8;

  f32x4 acc[4][4];
#pragma unroll
  for (int f = 0; f < 4; ++f)
#pragma unroll
    for (int g = 0; g < 4; ++g) acc[f][g] = (f32x4){0.f, 0.f, 0.f, 0.f};

  kloop97(pa, pb, As, Bs, acc, D_ / 64, wid, aoff, boff, sk0, sk1);

  float bias[4];
#pragma unroll
  for (int g = 0; g < 4; ++g) bias[g] = b1[e * F_ + n0 + wn * 64 + g * 16 + cidx];
  size_t hbase = (size_t)be * TK_ * F_;
#pragma unroll
  for (int f = 0; f < 4; ++f) {
#pragma unroll
    for (int r = 0; r < 4; ++r) {
      int lr = wm * 64 + f * 16 + kq * 4 + r;
      size_t hb = hbase + (size_t)(t0 + lr) * F_ + n0 + wn * 64 + cidx;
      float vs = 0.f, vss = 0.f;
#pragma unroll
      for (int g = 0; g < 4; ++g) {
        float v = acc[f][g][r] + bias[g];
        float gl = 0.5f * v * (1.0f + erff(v * 0.70710678118654752f));
        hbuf[hb + g * 16] = f2bf(gl);
        vs += gl;
        vss += gl * gl;
      }
#pragma unroll
      for (int off = 1; off < 16; off <<= 1) {
        vs += __shfl_xor(vs, off);
        vss += __shfl_xor(vss, off);
      }
      if (cidx == 0) {
        float2 o; o.x = vs; o.y = vss;
        sm[lr][wn] = o;
      }
    }
  }
  __syncthreads();
  if (tid < 128) {
    float2 a = sm[tid][0], b = sm[tid][1];
    float2 o; o.x = a.x + b.x; o.y = a.y + b.y;
    stats2[((size_t)be * TK_ + t0 + tid) * 16 + tn] = o;
  }
}

// ---------------- GEMM2: out = rstd*(h @ W2g) - rstd*mean*G + Bd + b2 -> weighted scatter ----------------
__global__ __launch_bounds__(256, 2) void gemm2_kernel(const u16* __restrict__ hbuf,
                                                       const u16* __restrict__ W2g,
                                                       const float* __restrict__ b2,
                                                       const int* __restrict__ idx,
                                                       const float* __restrict__ wts,
                                                       float* __restrict__ results,
                                                       const float2* __restrict__ stats2,
                                                       const float* __restrict__ G,
                                                       const float* __restrict__ Bd) {
  int p = blockIdx.x;
  int e = p & 7, slot = p >> 3;
  int tn = slot & 7, tm = (slot >> 3) & 3, bb = slot >> 5;
  int be = bb * 8 + e;
  int t0 = tm * 128, n0 = tn * 128;
  int tid = threadIdx.x, lane = tid & 63, wid = tid >> 6;
  int wm = wid >> 1, wn = wid & 1;
  int cidx = lane & 15, kq = lane >> 4;
  __shared__ u16 As[128 * 64];
  __shared__ u16 Bs[128 * 64];
  __shared__ float smean[128];
  __shared__ float srstd[128];

  // fold LN stats: mean/rstd per local row
  if (tid < 128) {
    const float2* sp = stats2 + ((size_t)be * TK_ + t0 + tid) * 16;
    float sum = 0.f, ss = 0.f;
#pragma unroll
    for (int j = 0; j < 16; ++j) {
      float2 v = sp[j];
      sum += v.x;
      ss += v.y;
    }
    float mean = sum * (1.f / F_);
    float var = ss * (1.f / F_) - mean * mean;
    smean[tid] = mean;
    srstd[tid] = rsqrtf(var + 1e-5f);
  }
  __syncthreads();

  int srow = tid >> 3;
  int kc = (tid & 7) ^ (srow & 7);
  const u16* pa[4];
  const u16* pb[4];
  const u16* asrc = hbuf + (size_t)be * TK_ * F_;
  const u16* bsrc = W2g + (size_t)e * D_ * F_;
#pragma unroll
  for (int q = 0; q < 4; ++q) {
    pa[q] = asrc + (size_t)(t0 + q * 32 + srow) * F_ + kc * 8;
    pb[q] = bsrc + (size_t)(n0 + q * 32 + srow) * F_ + kc * 8;
  }
  int aoff[4], boff[4];
#pragma unroll
  for (int f = 0; f < 4; ++f) {
    aoff[f] = (wm * 64 + f * 16 + cidx) * 64;
    boff[f] = (wn * 64 + f * 16 + cidx) * 64;
  }
  int sk0 = (kq ^ (cidx & 7)) * 8;
  int sk1 = ((4 + kq) ^ (cidx & 7)) * 8;

  f32x4 acc[4][4];
#pragma unroll
  for (int f = 0; f < 4; ++f)
#pragma unroll
    for (int g = 0; g < 4; ++g) acc[f][g] = (f32x4){0.f, 0.f, 0.f, 0.f};

  kloop97(pa, pb, As, Bs, acc, F_ / 64, wid, aoff, boff, sk0, sk1);

  int cb = n0 + wn * 64 + cidx;
  float b2v[4], Gv[4], Bdv[4];
#pragma unroll
  for (int g = 0; g < 4; ++g) {
    b2v[g] = b2[e * D_ + cb + g * 16];
    Gv[g] = G[e * D_ + cb + g * 16];
    Bdv[g] = Bd[e * D_ + cb + g * 16];
  }
#pragma unroll
  for (int f = 0; f < 4; ++f) {
#pragma unroll
    for (int r = 0; r < 4; ++r) {
      int lr = wm * 64 + f * 16 + kq * 4 + r;
      int trow = t0 + lr;
      int tok = idx[be * TK_ + trow];
      float wv = wts[be * TK_ + trow];
      float mean = smean[lr], rstd = srstd[lr];
      float* rrow = results + ((size_t)bb * S_ + tok) * D_ + cb;
#pragma unroll
      for (int g = 0; g < 4; ++g) {
        float out = rstd * acc[f][g][r] - rstd * mean * Gv[g] + Bdv[g] + b2v[g];
        unsafeAtomicAdd(rrow + g * 16, wv * out);
      }
    }
  }
}

extern "C" void kernel_launch(void* const* d_in, const int* in_sizes, int n_in,
                              void* d_out, int out_size, void* d_ws, size_t ws_size,
                              hipStream_t stream) {
  const float* x = (const float*)d_in[0];
  const float* Wr = (const float*)d_in[1];
  const float* W1 = (const float*)d_in[2];
  const float* b1 = (const float*)d_in[3];
  const float* gamma = (const float*)d_in[4];
  const float* beta = (const float*)d_in[5];
  const float* W2 = (const float*)d_in[6];
  const float* b2 = (const float*)d_in[7];

  float* results = (float*)d_out;
  float* logits = results + (size_t)B_ * S_ * D_;

  char* ws = (char*)d_ws;
  const size_t OFF_IDX = 0;                                       // 64 KB
  const size_t OFF_WTS = OFF_IDX + (size_t)B_ * E_ * TK_ * 4;     // 64 KB
  const size_t OFF_ST = OFF_WTS + (size_t)B_ * E_ * TK_ * 4;      // 2 MB stats2
  const size_t OFF_G = OFF_ST + (size_t)B_ * E_ * TK_ * 16 * 8;   // 32 KB
  const size_t OFF_BD = OFF_G + (size_t)E_ * D_ * 4;              // 32 KB
  const size_t OFF_R0 = OFF_BD + (size_t)E_ * D_ * 4;             // 32 MB: xb, then W2g
  const size_t OFF_R1 = OFF_R0 + (size_t)E_ * D_ * F_ * 2;        // 32 MB: W1t
  const size_t OFF_H = OFF_R1 + (size_t)E_ * D_ * F_ * 2;         // 64 MB: hbuf
  const size_t NEED = OFF_H + (size_t)B_ * E_ * TK_ * F_ * 2;
  if (ws_size < NEED) return;

  int* idx = (int*)(ws + OFF_IDX);
  float* wts = (float*)(ws + OFF_WTS);
  float2* stats2 = (float2*)(ws + OFF_ST);
  float* G = (float*)(ws + OFF_G);
  float* Bd = (float*)(ws + OFF_BD);
  u16* xb = (u16*)(ws + OFF_R0);
  u16* W2g = (u16*)(ws + OFF_R0);
  u16* W1t = (u16*)(ws + OFF_R1);
  u16* hbuf = (u16*)(ws + OFF_H);

  rc_kernel<<<dim3(B_ * S_ / 4), 256, 0, stream>>>(x, Wr, logits, xb, results);
  topk_kernel<<<dim3(B_ * E_), 1024, 0, stream>>>(logits, idx, wts);
  transpose_cvt_kernel<<<dim3(D_ / 32, F_ / 32, E_), 256, 0, stream>>>(
      W1, W1t, D_, F_, nullptr, nullptr, nullptr);
  gemm1_kernel<<<dim3(2048), 256, 0, stream>>>(xb, W1t, b1, idx, hbuf, stats2);
  // W2g overwrites xb region only after gemm1 completed (in-order stream)
  hipMemsetAsync(Bd, 0, (size_t)E_ * D_ * 4, stream);
  transpose_cvt_kernel<<<dim3(F_ / 32, D_ / 32, E_), 256, 0, stream>>>(
      W2, W2g, F_, D_, gamma, beta, Bd);
  gemv_g_kernel<<<dim3(E_ * D_ / 4), 256, 0, stream>>>(W2g, G);
  gemm2_kernel<<<dim3(1024), 256, 0, stream>>>(hbuf, W2g, b2, idx, wts, results,
                                               stats2, G, Bd);
}